// Round 1
// baseline (801.138 us; speedup 1.0000x reference)
//
#include <hip/hip_runtime.h>
#include <hip/hip_bf16.h>
#include <hip/hip_fp16.h>

#define B_   8
#define S_   4096
#define DD_  1024   // dst nodes
#define DIM_ 512
#define SCALE 0.044194173824159216f  // 1/sqrt(512)

typedef __bf16 bf16x8 __attribute__((ext_vector_type(8)));
typedef float  floatx4 __attribute__((ext_vector_type(4)));

#define LDK 40  // 32 + 8 pad (keeps 16B alignment, breaks pow2 bank stride)

__device__ inline unsigned short f2bf(float f) {
    union { float f; unsigned int u; } v; v.f = f;
    unsigned int r = v.u + 0x7fffu + ((v.u >> 16) & 1u);  // RNE
    return (unsigned short)(r >> 16);
}
__device__ inline float bf2f(unsigned short h) {
    union { unsigned int u; float f; } v; v.u = ((unsigned int)h) << 16;
    return v.f;
}
__device__ inline void store8bf(unsigned short* d, const float* f) {
    unsigned short tmp[8];
#pragma unroll
    for (int i = 0; i < 8; ++i) tmp[i] = f2bf(f[i]);
    *(uint4*)d = *(const uint4*)tmp;
}

// ---------------------------------------------------------------------------
// K1: Q = src @ W_route, P = src @ W_val   (blockIdx.z picks which)
// A: [32768, 512] fp32  B: [512, 512] fp32  C: bf16 out
// ---------------------------------------------------------------------------
__global__ __launch_bounds__(256) void k_qp(const float* __restrict__ src,
                                            const float* __restrict__ Wr,
                                            const float* __restrict__ Wv,
                                            unsigned short* __restrict__ Qb,
                                            unsigned short* __restrict__ Pb) {
    __shared__ unsigned short As[64 * LDK];
    __shared__ unsigned short Bs[64 * LDK];
    const int n0 = blockIdx.x * 64;
    const int m0 = blockIdx.y * 64;
    const float* Wm = blockIdx.z ? Wv : Wr;
    unsigned short* Out = blockIdx.z ? Pb : Qb;
    const int t = threadIdx.x;
    const int lane = t & 63, wave = t >> 6;

    floatx4 acc[4];
#pragma unroll
    for (int i = 0; i < 4; ++i) acc[i] = (floatx4){0.f, 0.f, 0.f, 0.f};

    for (int k0 = 0; k0 < DIM_; k0 += 32) {
        // stage A: As[m][k] = src[m0+m][k0+k]
        {
            const int r = t >> 2, cg = (t & 3) * 8;
            const float* g = src + (size_t)(m0 + r) * DIM_ + k0 + cg;
            float4 f0 = *(const float4*)g;
            float4 f1 = *(const float4*)(g + 4);
            float f[8] = {f0.x, f0.y, f0.z, f0.w, f1.x, f1.y, f1.z, f1.w};
            store8bf(&As[r * LDK + cg], f);
        }
        // stage B transposed: Bs[n][k] = W[k0+k][n0+n]
        {
            const int kk = t >> 3, ng = (t & 7) * 8;
            const float* g = Wm + (size_t)(k0 + kk) * DIM_ + n0 + ng;
            float4 f0 = *(const float4*)g;
            float4 f1 = *(const float4*)(g + 4);
            float f[8] = {f0.x, f0.y, f0.z, f0.w, f1.x, f1.y, f1.z, f1.w};
#pragma unroll
            for (int i = 0; i < 8; ++i) Bs[(ng + i) * LDK + kk] = f2bf(f[i]);
        }
        __syncthreads();
        const int mr = wave * 16 + (lane & 15);
        const int q = lane >> 4;
        bf16x8 a = *(const bf16x8*)&As[mr * LDK + q * 8];
#pragma unroll
        for (int nt = 0; nt < 4; ++nt) {
            bf16x8 b = *(const bf16x8*)&Bs[(nt * 16 + (lane & 15)) * LDK + q * 8];
            acc[nt] = __builtin_amdgcn_mfma_f32_16x16x32_bf16(a, b, acc[nt], 0, 0, 0);
        }
        __syncthreads();
    }
    const int col = lane & 15, q = lane >> 4;
#pragma unroll
    for (int nt = 0; nt < 4; ++nt)
#pragma unroll
        for (int i = 0; i < 4; ++i) {
            const int row = m0 + wave * 16 + q * 4 + i;
            Out[(size_t)row * DIM_ + n0 + nt * 16 + col] = f2bf(acc[nt][i]);
        }
}

// ---------------------------------------------------------------------------
// K2a: logits[b][s][kd] = (Q[b][s]·dst[b][kd]) * SCALE   -> fp16
// ---------------------------------------------------------------------------
__global__ __launch_bounds__(256) void k_logits(const unsigned short* __restrict__ Qb,
                                                const float* __restrict__ dst,
                                                __half* __restrict__ Lg) {
    __shared__ unsigned short As[64 * LDK];
    __shared__ unsigned short Bs[64 * LDK];
    const int n0 = blockIdx.x * 64;
    const int m0 = blockIdx.y * 64;
    const int b = blockIdx.z;
    const unsigned short* Q = Qb + (size_t)b * S_ * DIM_;
    const float* K = dst + (size_t)b * DD_ * DIM_;
    __half* L = Lg + (size_t)b * S_ * DD_;
    const int t = threadIdx.x;
    const int lane = t & 63, wave = t >> 6;

    floatx4 acc[4];
#pragma unroll
    for (int i = 0; i < 4; ++i) acc[i] = (floatx4){0.f, 0.f, 0.f, 0.f};

    for (int k0 = 0; k0 < DIM_; k0 += 32) {
        {  // A: As[m][k] = Q[m0+m][k0+k]  (already bf16, straight 16B copy)
            const int r = t >> 2, cg = (t & 3) * 8;
            *(uint4*)&As[r * LDK + cg] =
                *(const uint4*)(Q + (size_t)(m0 + r) * DIM_ + k0 + cg);
        }
        {  // B: Bs[n][k] = dst[n0+n][k0+k]  (row-major copy, fp32->bf16)
            const int r = t >> 2, cg = (t & 3) * 8;
            const float* g = K + (size_t)(n0 + r) * DIM_ + k0 + cg;
            float4 f0 = *(const float4*)g;
            float4 f1 = *(const float4*)(g + 4);
            float f[8] = {f0.x, f0.y, f0.z, f0.w, f1.x, f1.y, f1.z, f1.w};
            store8bf(&Bs[r * LDK + cg], f);
        }
        __syncthreads();
        const int mr = wave * 16 + (lane & 15);
        const int q = lane >> 4;
        bf16x8 a = *(const bf16x8*)&As[mr * LDK + q * 8];
#pragma unroll
        for (int nt = 0; nt < 4; ++nt) {
            bf16x8 b = *(const bf16x8*)&Bs[(nt * 16 + (lane & 15)) * LDK + q * 8];
            acc[nt] = __builtin_amdgcn_mfma_f32_16x16x32_bf16(a, b, acc[nt], 0, 0, 0);
        }
        __syncthreads();
    }
    const int col = lane & 15, q = lane >> 4;
#pragma unroll
    for (int nt = 0; nt < 4; ++nt)
#pragma unroll
        for (int i = 0; i < 4; ++i) {
            const int row = m0 + wave * 16 + q * 4 + i;
            L[(size_t)row * DD_ + n0 + nt * 16 + col] = __float2half(acc[nt][i] * SCALE);
        }
}

// ---------------------------------------------------------------------------
// K2b: per-(b,s)-row softmax over 1024 dst; w = softmax * softplus(state)
// in-place: fp16 logits -> bf16 w (same buffer)
// ---------------------------------------------------------------------------
__global__ __launch_bounds__(256) void k_softmax(const float* __restrict__ state,
                                                 void* Lw) {
    const int row = blockIdx.x * 4 + (threadIdx.x >> 6);  // flat b*S+s
    const int lane = threadIdx.x & 63;
    const __half* L = (const __half*)Lw + (size_t)row * DD_;
    unsigned short* W = (unsigned short*)Lw + (size_t)row * DD_;

    float x[16];
#pragma unroll
    for (int j = 0; j < 16; ++j) x[j] = __half2float(L[lane + 64 * j]);

    float m = -1e30f;
#pragma unroll
    for (int j = 0; j < 16; ++j) m = fmaxf(m, x[j]);
#pragma unroll
    for (int off = 32; off; off >>= 1) m = fmaxf(m, __shfl_xor(m, off));

    float l = 0.f;
#pragma unroll
    for (int j = 0; j < 16; ++j) { x[j] = expf(x[j] - m); l += x[j]; }
#pragma unroll
    for (int off = 32; off; off >>= 1) l += __shfl_xor(l, off);

    const float st = state[row];
    const float sp = (st > 15.f) ? st : log1pf(expf(st));  // softplus
    const float scale = sp / l;
#pragma unroll
    for (int j = 0; j < 16; ++j) W[lane + 64 * j] = f2bf(x[j] * scale);
}

// ---------------------------------------------------------------------------
// K2c: delta_state[b][kd] = sum_s w[b][s][kd] * state[b][s]
// ---------------------------------------------------------------------------
__global__ __launch_bounds__(256) void k_dstate(const unsigned short* __restrict__ Wrt,
                                                const float* __restrict__ state,
                                                float* __restrict__ out) {
    const int b = blockIdx.y;
    const int kd = blockIdx.x * 256 + threadIdx.x;
    const unsigned short* w = Wrt + (size_t)b * S_ * DD_ + kd;
    const float* st = state + (size_t)b * S_;
    float a0 = 0.f, a1 = 0.f, a2 = 0.f, a3 = 0.f;
    for (int s = 0; s < S_; s += 4) {
        a0 += bf2f(w[(size_t)(s + 0) * DD_]) * st[s + 0];
        a1 += bf2f(w[(size_t)(s + 1) * DD_]) * st[s + 1];
        a2 += bf2f(w[(size_t)(s + 2) * DD_]) * st[s + 2];
        a3 += bf2f(w[(size_t)(s + 3) * DD_]) * st[s + 3];
    }
    out[(size_t)b * DD_ + kd] = (a0 + a1) + (a2 + a3);
}

// ---------------------------------------------------------------------------
// K3: delta_val[b] = w[b]^T (1024x4096) @ P[b] (4096x512), fp32 out
// ---------------------------------------------------------------------------
__global__ __launch_bounds__(256) void k_dval(const unsigned short* __restrict__ Wrt,
                                              const unsigned short* __restrict__ Pb,
                                              float* __restrict__ out) {
    __shared__ unsigned short As[64 * LDK];
    __shared__ unsigned short Bs[64 * LDK];
    const int n0 = blockIdx.x * 64;   // dim
    const int m0 = blockIdx.y * 64;   // dst node
    const int b = blockIdx.z;
    const unsigned short* w = Wrt + (size_t)b * S_ * DD_;
    const unsigned short* P = Pb + (size_t)b * S_ * DIM_;
    float* O = out + (size_t)b * DD_ * DIM_;
    const int t = threadIdx.x;
    const int lane = t & 63, wave = t >> 6;

    floatx4 acc[4];
#pragma unroll
    for (int i = 0; i < 4; ++i) acc[i] = (floatx4){0.f, 0.f, 0.f, 0.f};

    for (int k0 = 0; k0 < S_; k0 += 32) {
        {  // A transposed: As[m][kk] = w[k0+kk][m0+m]
            const int kk = t >> 3, mg = (t & 7) * 8;
            uint4 v = *(const uint4*)(w + (size_t)(k0 + kk) * DD_ + m0 + mg);
            const unsigned short* e = (const unsigned short*)&v;
#pragma unroll
            for (int i = 0; i < 8; ++i) As[(mg + i) * LDK + kk] = e[i];
        }
        {  // B transposed: Bs[n][kk] = P[k0+kk][n0+n]
            const int kk = t >> 3, ng = (t & 7) * 8;
            uint4 v = *(const uint4*)(P + (size_t)(k0 + kk) * DIM_ + n0 + ng);
            const unsigned short* e = (const unsigned short*)&v;
#pragma unroll
            for (int i = 0; i < 8; ++i) Bs[(ng + i) * LDK + kk] = e[i];
        }
        __syncthreads();
        const int mr = wave * 16 + (lane & 15);
        const int q = lane >> 4;
        bf16x8 a = *(const bf16x8*)&As[mr * LDK + q * 8];
#pragma unroll
        for (int nt = 0; nt < 4; ++nt) {
            bf16x8 bfr = *(const bf16x8*)&Bs[(nt * 16 + (lane & 15)) * LDK + q * 8];
            acc[nt] = __builtin_amdgcn_mfma_f32_16x16x32_bf16(a, bfr, acc[nt], 0, 0, 0);
        }
        __syncthreads();
    }
    const int col = lane & 15, q = lane >> 4;
#pragma unroll
    for (int nt = 0; nt < 4; ++nt)
#pragma unroll
        for (int i = 0; i < 4; ++i) {
            const int row = m0 + wave * 16 + q * 4 + i;
            O[(size_t)row * DIM_ + n0 + nt * 16 + col] = acc[nt][i];
        }
}

// ---------------------------------------------------------------------------
extern "C" void kernel_launch(void* const* d_in, const int* in_sizes, int n_in,
                              void* d_out, int out_size, void* d_ws, size_t ws_size,
                              hipStream_t stream) {
    const float* src   = (const float*)d_in[0];   // [B,S,DIM]
    const float* state = (const float*)d_in[1];   // [B,S]
    const float* dst   = (const float*)d_in[2];   // [B,D,DIM]
    const float* Wr    = (const float*)d_in[3];   // [DIM,DIM]
    const float* Wv    = (const float*)d_in[4];   // [DIM,DIM]

    // workspace layout (128 MiB total):
    unsigned short* Qb = (unsigned short*)d_ws;                  // [B*S, DIM] bf16
    unsigned short* Pb = Qb + (size_t)B_ * S_ * DIM_;            // [B*S, DIM] bf16
    void* Lw = (void*)(Pb + (size_t)B_ * S_ * DIM_);             // [B,S,D] fp16 -> bf16

    float* d_state = (float*)d_out;               // [B, D]
    float* d_val   = (float*)d_out + B_ * DD_;    // [B, D, DIM]

    k_qp<<<dim3(DIM_ / 64, (B_ * S_) / 64, 2), 256, 0, stream>>>(src, Wr, Wv, Qb, Pb);
    k_logits<<<dim3(DD_ / 64, S_ / 64, B_), 256, 0, stream>>>(Qb, dst, (__half*)Lw);
    k_softmax<<<dim3((B_ * S_) / 4), 256, 0, stream>>>(state, Lw);
    k_dstate<<<dim3(DD_ / 256, B_), 256, 0, stream>>>((const unsigned short*)Lw, state, d_state);
    k_dval<<<dim3(DIM_ / 64, DD_ / 64, B_), 256, 0, stream>>>((const unsigned short*)Lw, Pb, d_val);
}

// Round 2
// 517.191 us; speedup vs baseline: 1.5490x; 1.5490x over previous
//
#include <hip/hip_runtime.h>
#include <hip/hip_fp16.h>

#define B_   8
#define S_   4096
#define DD_  1024   // dst nodes
#define DIM_ 512
#define SCALE 0.044194173824159216f  // 1/sqrt(512)

typedef __bf16 bf16x8 __attribute__((ext_vector_type(8)));
typedef float  floatx4 __attribute__((ext_vector_type(4)));

__device__ inline unsigned short f2bf(float f) {
    union { float f; unsigned int u; } v; v.f = f;
    unsigned int r = v.u + 0x7fffu + ((v.u >> 16) & 1u);  // RNE
    return (unsigned short)(r >> 16);
}
__device__ inline float bf2f(unsigned short h) {
    union { unsigned int u; float f; } v; v.u = ((unsigned int)h) << 16;
    return v.f;
}
// 8 fp32 -> 8 bf16 packed in a uint4
__device__ inline uint4 cvt8(const float* __restrict__ g) {
    float4 f0 = *(const float4*)g;
    float4 f1 = *(const float4*)(g + 4);
    unsigned short tmp[8] = {f2bf(f0.x), f2bf(f0.y), f2bf(f0.z), f2bf(f0.w),
                             f2bf(f1.x), f2bf(f1.y), f2bf(f1.z), f2bf(f1.w)};
    return *(const uint4*)tmp;
}

// ---------------------------------------------------------------------------
// k_wt: WT[e][d] = W[d][e], fp32 -> bf16.  z=0: W_route, z=1: W_val. 1MB total.
// ---------------------------------------------------------------------------
__global__ __launch_bounds__(256) void k_wt(const float* __restrict__ Wr,
                                            const float* __restrict__ Wv,
                                            unsigned short* __restrict__ WrT,
                                            unsigned short* __restrict__ WvT) {
    __shared__ float Ts[64 * 68];
    const float* W = blockIdx.z ? Wv : Wr;
    unsigned short* WT = blockIdx.z ? WvT : WrT;
    const int d0 = blockIdx.x * 64, e0 = blockIdx.y * 64;
    const int t = threadIdx.x;
    {
        const int r = t >> 2, c0 = (t & 3) * 16;
        const float* g = W + (size_t)(d0 + r) * DIM_ + e0 + c0;
#pragma unroll
        for (int i = 0; i < 4; ++i)
            *(float4*)&Ts[r * 68 + c0 + i * 4] = *(const float4*)(g + i * 4);
    }
    __syncthreads();
    {
        const int rr = t >> 2, c0 = (t & 3) * 16;  // rr = e-local, c = d-local
        unsigned short tmp[16];
#pragma unroll
        for (int j = 0; j < 16; ++j) tmp[j] = f2bf(Ts[(c0 + j) * 68 + rr]);
        unsigned short* o = WT + (size_t)(e0 + rr) * DIM_ + d0 + c0;
        *(uint4*)o = *(const uint4*)tmp;
        *(uint4*)(o + 8) = *(const uint4*)(tmp + 8);
    }
}

// ---------------------------------------------------------------------------
// k_q: Q[s][e] = sum_d src[s][d] * Wr[d][e]   (B-operand = WrT[e][d], k-minor)
// ---------------------------------------------------------------------------
__global__ __launch_bounds__(256) void k_q(const float* __restrict__ src,
                                           const unsigned short* __restrict__ WrT,
                                           unsigned short* __restrict__ Qb) {
    __shared__ unsigned short As[64 * 32];
    __shared__ unsigned short Bs[64 * 32];
    const int n0 = blockIdx.x * 64;         // e
    const int m0 = blockIdx.y * 64;         // flat b*s
    const int t = threadIdx.x, lane = t & 63, wave = t >> 6;
    const int r = t >> 2, cg = (t & 3) * 8;

    floatx4 acc[4];
#pragma unroll
    for (int i = 0; i < 4; ++i) acc[i] = (floatx4){0.f, 0.f, 0.f, 0.f};

    for (int k0 = 0; k0 < DIM_; k0 += 32) {
        *(uint4*)&As[r * 32 + cg] = cvt8(src + (size_t)(m0 + r) * DIM_ + k0 + cg);
        *(uint4*)&Bs[r * 32 + cg] =
            *(const uint4*)(WrT + (size_t)(n0 + r) * DIM_ + k0 + cg);
        __syncthreads();
        bf16x8 a = *(const bf16x8*)&As[(wave * 16 + (lane & 15)) * 32 + (lane >> 4) * 8];
#pragma unroll
        for (int nt = 0; nt < 4; ++nt) {
            bf16x8 b = *(const bf16x8*)&Bs[(nt * 16 + (lane & 15)) * 32 + (lane >> 4) * 8];
            acc[nt] = __builtin_amdgcn_mfma_f32_16x16x32_bf16(a, b, acc[nt], 0, 0, 0);
        }
        __syncthreads();
    }
    const int col = lane & 15, q = lane >> 4;
#pragma unroll
    for (int nt = 0; nt < 4; ++nt)
#pragma unroll
        for (int i = 0; i < 4; ++i)
            Qb[(size_t)(m0 + wave * 16 + q * 4 + i) * DIM_ + n0 + nt * 16 + col] =
                f2bf(acc[nt][i]);
}

// ---------------------------------------------------------------------------
// k_pt: PT[e][s] = sum_d WvT[e][d] * src[s][d]   (per batch)
// ---------------------------------------------------------------------------
__global__ __launch_bounds__(256) void k_pt(const unsigned short* __restrict__ WvT,
                                            const float* __restrict__ src,
                                            unsigned short* __restrict__ PTb) {
    __shared__ unsigned short As[64 * 32];
    __shared__ unsigned short Bs[64 * 32];
    const int n0 = blockIdx.x * 64;         // s
    const int m0 = blockIdx.y * 64;         // e
    const int b = blockIdx.z;
    const float* S = src + (size_t)b * S_ * DIM_;
    unsigned short* PT = PTb + (size_t)b * DIM_ * S_;
    const int t = threadIdx.x, lane = t & 63, wave = t >> 6;
    const int r = t >> 2, cg = (t & 3) * 8;

    floatx4 acc[4];
#pragma unroll
    for (int i = 0; i < 4; ++i) acc[i] = (floatx4){0.f, 0.f, 0.f, 0.f};

    for (int k0 = 0; k0 < DIM_; k0 += 32) {
        *(uint4*)&As[r * 32 + cg] =
            *(const uint4*)(WvT + (size_t)(m0 + r) * DIM_ + k0 + cg);
        *(uint4*)&Bs[r * 32 + cg] = cvt8(S + (size_t)(n0 + r) * DIM_ + k0 + cg);
        __syncthreads();
        bf16x8 a = *(const bf16x8*)&As[(wave * 16 + (lane & 15)) * 32 + (lane >> 4) * 8];
#pragma unroll
        for (int nt = 0; nt < 4; ++nt) {
            bf16x8 b = *(const bf16x8*)&Bs[(nt * 16 + (lane & 15)) * 32 + (lane >> 4) * 8];
            acc[nt] = __builtin_amdgcn_mfma_f32_16x16x32_bf16(a, b, acc[nt], 0, 0, 0);
        }
        __syncthreads();
    }
    const int col = lane & 15, q = lane >> 4;
#pragma unroll
    for (int nt = 0; nt < 4; ++nt)
#pragma unroll
        for (int i = 0; i < 4; ++i)
            PT[(size_t)(m0 + wave * 16 + q * 4 + i) * S_ + n0 + nt * 16 + col] =
                f2bf(acc[nt][i]);
}

// ---------------------------------------------------------------------------
// k_logitsT: LT[dd][s] = SCALE * sum_d dst[dd][d] * Q[s][d]  -> fp16 (per batch)
// ---------------------------------------------------------------------------
__global__ __launch_bounds__(256) void k_logitsT(const float* __restrict__ dst,
                                                 const unsigned short* __restrict__ Qb,
                                                 __half* __restrict__ LTb) {
    __shared__ unsigned short As[64 * 32];
    __shared__ unsigned short Bs[64 * 32];
    const int n0 = blockIdx.x * 64;         // s
    const int m0 = blockIdx.y * 64;         // dd
    const int b = blockIdx.z;
    const float* K = dst + (size_t)b * DD_ * DIM_;
    const unsigned short* Q = Qb + (size_t)b * S_ * DIM_;
    __half* LT = LTb + (size_t)b * DD_ * S_;
    const int t = threadIdx.x, lane = t & 63, wave = t >> 6;
    const int r = t >> 2, cg = (t & 3) * 8;

    floatx4 acc[4];
#pragma unroll
    for (int i = 0; i < 4; ++i) acc[i] = (floatx4){0.f, 0.f, 0.f, 0.f};

    for (int k0 = 0; k0 < DIM_; k0 += 32) {
        *(uint4*)&As[r * 32 + cg] = cvt8(K + (size_t)(m0 + r) * DIM_ + k0 + cg);
        *(uint4*)&Bs[r * 32 + cg] =
            *(const uint4*)(Q + (size_t)(n0 + r) * DIM_ + k0 + cg);
        __syncthreads();
        bf16x8 a = *(const bf16x8*)&As[(wave * 16 + (lane & 15)) * 32 + (lane >> 4) * 8];
#pragma unroll
        for (int nt = 0; nt < 4; ++nt) {
            bf16x8 b = *(const bf16x8*)&Bs[(nt * 16 + (lane & 15)) * 32 + (lane >> 4) * 8];
            acc[nt] = __builtin_amdgcn_mfma_f32_16x16x32_bf16(a, b, acc[nt], 0, 0, 0);
        }
        __syncthreads();
    }
    const int col = lane & 15, q = lane >> 4;
#pragma unroll
    for (int nt = 0; nt < 4; ++nt)
#pragma unroll
        for (int i = 0; i < 4; ++i)
            LT[(size_t)(m0 + wave * 16 + q * 4 + i) * S_ + n0 + nt * 16 + col] =
                __float2half(acc[nt][i] * SCALE);
}

// ---------------------------------------------------------------------------
// k_softmax_col: column softmax over LT (dd dim), * softplus(state), in-place
// fp16 logits -> bf16 w.  Block: 64 columns x 4 waves (each wave 256 dd rows).
// ---------------------------------------------------------------------------
__global__ __launch_bounds__(256) void k_softmax_col(const float* __restrict__ state,
                                                     void* __restrict__ LTw) {
    __shared__ float Ms[4][64];
    __shared__ float Ls[4][64];
    const int b = blockIdx.y;
    const int s0 = blockIdx.x * 64;
    const int lane = threadIdx.x & 63, wave = threadIdx.x >> 6;
    const int s = s0 + lane;
    const __half* L = (const __half*)LTw + (size_t)b * DD_ * S_ + s;
    unsigned short* W = (unsigned short*)LTw + (size_t)b * DD_ * S_ + s;

    // pass 1: online max/sum over this wave's dd range
    float m = -1e30f, l = 0.f;
    const int dd0 = wave * (DD_ / 4);
#pragma unroll 4
    for (int i = 0; i < DD_ / 4; ++i) {
        float x = __half2float(L[(size_t)(dd0 + i) * S_]);
        float nm = fmaxf(m, x);
        l = l * __expf(m - nm) + __expf(x - nm);
        m = nm;
    }
    Ms[wave][lane] = m;
    Ls[wave][lane] = l;
    __syncthreads();

    // combine 4 wave-partials (redundantly in each wave)
    float M = fmaxf(fmaxf(Ms[0][lane], Ms[1][lane]), fmaxf(Ms[2][lane], Ms[3][lane]));
    float Ltot = 0.f;
#pragma unroll
    for (int j = 0; j < 4; ++j) Ltot += Ls[j][lane] * __expf(Ms[j][lane] - M);

    const float st = state[(size_t)b * S_ + s];
    const float sp = (st > 15.f) ? st : log1pf(__expf(st));
    const float scale = sp / Ltot;

    // pass 2: w = exp(x - M) * scale, write bf16 in place
#pragma unroll 4
    for (int i = 0; i < DD_ / 4; ++i) {
        float x = __half2float(L[(size_t)(dd0 + i) * S_]);
        W[(size_t)(dd0 + i) * S_] = f2bf(__expf(x - M) * scale);
    }
}

// ---------------------------------------------------------------------------
// k_dstate: delta_state[b][dd] = sum_s wT[dd][s] * state[b][s]
// one wave per dd row, lanes over s (uint4 loads), shuffle reduce
// ---------------------------------------------------------------------------
__global__ __launch_bounds__(256) void k_dstate(const unsigned short* __restrict__ wT,
                                                const float* __restrict__ state,
                                                float* __restrict__ out) {
    const int b = blockIdx.y;
    const int dd = blockIdx.x * 4 + (threadIdx.x >> 6);
    const int lane = threadIdx.x & 63;
    const unsigned short* row = wT + (size_t)b * DD_ * S_ + (size_t)dd * S_;
    const float* st = state + (size_t)b * S_;

    float acc = 0.f;
#pragma unroll
    for (int it = 0; it < S_ / 512; ++it) {
        const int s = it * 512 + lane * 8;
        uint4 v = *(const uint4*)(row + s);
        const unsigned short* e = (const unsigned short*)&v;
        float4 f0 = *(const float4*)(st + s);
        float4 f1 = *(const float4*)(st + s + 4);
        acc += bf2f(e[0]) * f0.x + bf2f(e[1]) * f0.y + bf2f(e[2]) * f0.z +
               bf2f(e[3]) * f0.w + bf2f(e[4]) * f1.x + bf2f(e[5]) * f1.y +
               bf2f(e[6]) * f1.z + bf2f(e[7]) * f1.w;
    }
#pragma unroll
    for (int off = 32; off; off >>= 1) acc += __shfl_down(acc, off);
    if (lane == 0) out[(size_t)b * DD_ + dd] = acc;
}

// ---------------------------------------------------------------------------
// k_dval: dval[dd][e] = sum_s wT[dd][s] * PT[e][s]   (per batch, fp32 out)
// ---------------------------------------------------------------------------
__global__ __launch_bounds__(256) void k_dval(const unsigned short* __restrict__ wTb,
                                              const unsigned short* __restrict__ PTb,
                                              float* __restrict__ out) {
    __shared__ unsigned short As[64 * 32];
    __shared__ unsigned short Bs[64 * 32];
    const int n0 = blockIdx.x * 64;         // e
    const int m0 = blockIdx.y * 64;         // dd
    const int b = blockIdx.z;
    const unsigned short* wT = wTb + (size_t)b * DD_ * S_;
    const unsigned short* PT = PTb + (size_t)b * DIM_ * S_;
    float* O = out + (size_t)b * DD_ * DIM_;
    const int t = threadIdx.x, lane = t & 63, wave = t >> 6;
    const int r = t >> 2, cg = (t & 3) * 8;

    floatx4 acc[4];
#pragma unroll
    for (int i = 0; i < 4; ++i) acc[i] = (floatx4){0.f, 0.f, 0.f, 0.f};

    for (int k0 = 0; k0 < S_; k0 += 32) {
        *(uint4*)&As[r * 32 + cg] =
            *(const uint4*)(wT + (size_t)(m0 + r) * S_ + k0 + cg);
        *(uint4*)&Bs[r * 32 + cg] =
            *(const uint4*)(PT + (size_t)(n0 + r) * S_ + k0 + cg);
        __syncthreads();
        bf16x8 a = *(const bf16x8*)&As[(wave * 16 + (lane & 15)) * 32 + (lane >> 4) * 8];
#pragma unroll
        for (int nt = 0; nt < 4; ++nt) {
            bf16x8 bfr = *(const bf16x8*)&Bs[(nt * 16 + (lane & 15)) * 32 + (lane >> 4) * 8];
            acc[nt] = __builtin_amdgcn_mfma_f32_16x16x32_bf16(a, bfr, acc[nt], 0, 0, 0);
        }
        __syncthreads();
    }
    const int col = lane & 15, q = lane >> 4;
#pragma unroll
    for (int nt = 0; nt < 4; ++nt)
#pragma unroll
        for (int i = 0; i < 4; ++i)
            O[(size_t)(m0 + wave * 16 + q * 4 + i) * DIM_ + n0 + nt * 16 + col] =
                acc[nt][i];
}

// ---------------------------------------------------------------------------
extern "C" void kernel_launch(void* const* d_in, const int* in_sizes, int n_in,
                              void* d_out, int out_size, void* d_ws, size_t ws_size,
                              hipStream_t stream) {
    const float* src   = (const float*)d_in[0];   // [B,S,DIM]
    const float* state = (const float*)d_in[1];   // [B,S]
    const float* dst   = (const float*)d_in[2];   // [B,D,DIM]
    const float* Wr    = (const float*)d_in[3];   // [DIM,DIM]
    const float* Wv    = (const float*)d_in[4];   // [DIM,DIM]

    // workspace (total 128 MiB):
    //   Q   [B,S,DIM]  bf16  32 MB
    //   PT  [B,DIM,S]  bf16  32 MB
    //   LT  [B,DD,S]   fp16  64 MB  (becomes wT bf16 in place)
    //   WrT/WvT overlap LT's last 1 MB (consumed before LT is written)
    unsigned short* Qb  = (unsigned short*)d_ws;
    unsigned short* PTb = Qb + (size_t)B_ * S_ * DIM_;
    unsigned short* LT  = PTb + (size_t)B_ * DIM_ * S_;
    const size_t lt_elems = (size_t)B_ * DD_ * S_;           // 33.5M shorts
    unsigned short* WrT = LT + lt_elems - 2 * (size_t)DIM_ * DIM_;
    unsigned short* WvT = WrT + (size_t)DIM_ * DIM_;

    float* d_state = (float*)d_out;               // [B, DD]
    float* d_val   = (float*)d_out + B_ * DD_;    // [B, DD, DIM]

    k_wt<<<dim3(DIM_ / 64, DIM_ / 64, 2), 256, 0, stream>>>(Wr, Wv, WrT, WvT);
    k_q<<<dim3(DIM_ / 64, (B_ * S_) / 64), 256, 0, stream>>>(src, WrT, Qb);
    k_pt<<<dim3(S_ / 64, DIM_ / 64, B_), 256, 0, stream>>>(WvT, src, PTb);
    k_logitsT<<<dim3(S_ / 64, DD_ / 64, B_), 256, 0, stream>>>(dst, Qb, (__half*)LT);
    k_softmax_col<<<dim3(S_ / 64, B_), 256, 0, stream>>>(state, (void*)LT);
    k_dstate<<<dim3(DD_ / 4, B_), 256, 0, stream>>>(LT, state, d_state);
    k_dval<<<dim3(DIM_ / 64, DD_ / 64, B_), 256, 0, stream>>>(LT, PTb, d_val);
}

// Round 3
// 417.899 us; speedup vs baseline: 1.9171x; 1.2376x over previous
//
#include <hip/hip_runtime.h>
#include <hip/hip_fp16.h>

#define B_   8
#define S_   4096
#define DD_  1024   // dst nodes
#define DIM_ 512
#define SCALE 0.044194173824159216f  // 1/sqrt(512)

typedef __bf16 bf16x8 __attribute__((ext_vector_type(8)));
typedef float  floatx4 __attribute__((ext_vector_type(4)));

__device__ inline unsigned short f2bf(float f) {
    union { float f; unsigned int u; } v; v.f = f;
    unsigned int r = v.u + 0x7fffu + ((v.u >> 16) & 1u);  // RNE
    return (unsigned short)(r >> 16);
}
__device__ inline float bf2f(unsigned short h) {
    union { unsigned int u; float f; } v; v.u = ((unsigned int)h) << 16;
    return v.f;
}
__device__ inline uint4 cvt8(const float* __restrict__ g) {
    float4 f0 = *(const float4*)g;
    float4 f1 = *(const float4*)(g + 4);
    unsigned short tmp[8] = {f2bf(f0.x), f2bf(f0.y), f2bf(f0.z), f2bf(f0.w),
                             f2bf(f1.x), f2bf(f1.y), f2bf(f1.z), f2bf(f1.w)};
    return *(const uint4*)tmp;
}
// async global->LDS, 16B per lane; lds base must be wave-uniform
__device__ inline void async16(unsigned short* lds, const unsigned short* g) {
    __builtin_amdgcn_global_load_lds(
        (const __attribute__((address_space(1))) void*)g,
        (__attribute__((address_space(3))) void*)lds, 16, 0, 0);
}

// ---------------------------------------------------------------------------
// 128x128xK mainloop, BK=32, 256 threads (2x2 waves, each 4x4 MFMA tiles).
// AF32/BF32: 1 = operand is fp32 (stage via cvt8 store), 0 = bf16 (async16).
// LDS layout: [row][32] halfwords, unpadded; flat byte offset = tid*16 per round.
// ---------------------------------------------------------------------------
template <int AF32, int BF32>
__device__ inline void mainloop(unsigned short* As, unsigned short* Bs,
                                const void* Ap, size_t lda,
                                const void* Bp, size_t ldb,
                                int kIters, floatx4 (&acc)[4][4]) {
    const int t = threadIdx.x, lane = t & 63, wave = t >> 6;
    const int rA = t >> 2, cA = (t & 3) * 8;
    const int mrow = (wave >> 1) * 64, ncol = (wave & 1) * 64;
    const int fr = lane & 15, fk = (lane >> 4) * 8;

    const unsigned short* gA16 = nullptr; const float* gA32 = nullptr;
    const unsigned short* gB16 = nullptr; const float* gB32 = nullptr;
    if (AF32) gA32 = (const float*)Ap + (size_t)rA * lda + cA;
    else      gA16 = (const unsigned short*)Ap + (size_t)rA * lda + cA;
    if (BF32) gB32 = (const float*)Bp + (size_t)rA * lda * 0 + (size_t)rA * ldb + cA;
    else      gB16 = (const unsigned short*)Bp + (size_t)rA * ldb + cA;

    unsigned short* ldsA = As + wave * 512;   // halfwords; round1 at +2048
    unsigned short* ldsB = Bs + wave * 512;

    for (int kt = 0; kt < kIters; ++kt) {
        if (AF32) {
            *(uint4*)&As[t * 8]        = cvt8(gA32);
            *(uint4*)&As[2048 + t * 8] = cvt8(gA32 + 64 * lda);
            gA32 += 32;
        } else {
            async16(ldsA,        gA16);
            async16(ldsA + 2048, gA16 + 64 * lda);
            gA16 += 32;
        }
        if (BF32) {
            *(uint4*)&Bs[t * 8]        = cvt8(gB32);
            *(uint4*)&Bs[2048 + t * 8] = cvt8(gB32 + 64 * ldb);
            gB32 += 32;
        } else {
            async16(ldsB,        gB16);
            async16(ldsB + 2048, gB16 + 64 * ldb);
            gB16 += 32;
        }
        __syncthreads();
        bf16x8 af[4], bfr[4];
#pragma unroll
        for (int i = 0; i < 4; ++i)
            af[i] = *(const bf16x8*)&As[(mrow + i * 16 + fr) * 32 + fk];
#pragma unroll
        for (int j = 0; j < 4; ++j)
            bfr[j] = *(const bf16x8*)&Bs[(ncol + j * 16 + fr) * 32 + fk];
#pragma unroll
        for (int i = 0; i < 4; ++i)
#pragma unroll
            for (int j = 0; j < 4; ++j)
                acc[i][j] = __builtin_amdgcn_mfma_f32_16x16x32_bf16(af[i], bfr[j],
                                                                    acc[i][j], 0, 0, 0);
        __syncthreads();
    }
}

#define EPILOGUE_COORDS                                     \
    const int lane = threadIdx.x & 63, wave = threadIdx.x >> 6; \
    const int mrow = (wave >> 1) * 64, ncol = (wave & 1) * 64;  \
    const int col = lane & 15, q = lane >> 4;

#define ACC_INIT                                            \
    floatx4 acc[4][4];                                      \
    _Pragma("unroll") for (int i = 0; i < 4; ++i)           \
        _Pragma("unroll") for (int j = 0; j < 4; ++j)       \
            acc[i][j] = (floatx4){0.f, 0.f, 0.f, 0.f};

// ---------------------------------------------------------------------------
// k_wt: WT[e][d] = W[d][e], fp32 -> bf16
// ---------------------------------------------------------------------------
__global__ __launch_bounds__(256) void k_wt(const float* __restrict__ Wr,
                                            const float* __restrict__ Wv,
                                            unsigned short* __restrict__ WrT,
                                            unsigned short* __restrict__ WvT) {
    __shared__ float Ts[64 * 68];
    const float* W = blockIdx.z ? Wv : Wr;
    unsigned short* WT = blockIdx.z ? WvT : WrT;
    const int d0 = blockIdx.x * 64, e0 = blockIdx.y * 64;
    const int t = threadIdx.x;
    {
        const int r = t >> 2, c0 = (t & 3) * 16;
        const float* g = W + (size_t)(d0 + r) * DIM_ + e0 + c0;
#pragma unroll
        for (int i = 0; i < 4; ++i)
            *(float4*)&Ts[r * 68 + c0 + i * 4] = *(const float4*)(g + i * 4);
    }
    __syncthreads();
    {
        const int rr = t >> 2, c0 = (t & 3) * 16;
        unsigned short tmp[16];
#pragma unroll
        for (int j = 0; j < 16; ++j) tmp[j] = f2bf(Ts[(c0 + j) * 68 + rr]);
        unsigned short* o = WT + (size_t)(e0 + rr) * DIM_ + d0 + c0;
        *(uint4*)o = *(const uint4*)tmp;
        *(uint4*)(o + 8) = *(const uint4*)(tmp + 8);
    }
}

// ---------------------------------------------------------------------------
// k_q: Q[s][e] = src[s][:] . WrT[e][:]
// ---------------------------------------------------------------------------
__global__ __launch_bounds__(256) void k_q(const float* __restrict__ src,
                                           const unsigned short* __restrict__ WrT,
                                           unsigned short* __restrict__ Qb) {
    __shared__ unsigned short As[128 * 32];
    __shared__ unsigned short Bs[128 * 32];
    const int n0 = blockIdx.x * 128, m0 = blockIdx.y * 128;
    ACC_INIT
    mainloop<1, 0>(As, Bs, src + (size_t)m0 * DIM_, DIM_,
                   WrT + (size_t)n0 * DIM_, DIM_, DIM_ / 32, acc);
    EPILOGUE_COORDS
#pragma unroll
    for (int i = 0; i < 4; ++i)
#pragma unroll
        for (int j = 0; j < 4; ++j)
#pragma unroll
            for (int r = 0; r < 4; ++r)
                Qb[(size_t)(m0 + mrow + i * 16 + q * 4 + r) * DIM_ +
                   n0 + ncol + j * 16 + col] = f2bf(acc[i][j][r]);
}

// ---------------------------------------------------------------------------
// k_logitsT: LT[dd][s] = SCALE * dst[dd][:] . Q[s][:]  -> fp16 (per batch)
// ---------------------------------------------------------------------------
__global__ __launch_bounds__(256) void k_logitsT(const float* __restrict__ dst,
                                                 const unsigned short* __restrict__ Qb,
                                                 __half* __restrict__ LTb) {
    __shared__ unsigned short As[128 * 32];
    __shared__ unsigned short Bs[128 * 32];
    const int n0 = blockIdx.x * 128, m0 = blockIdx.y * 128, b = blockIdx.z;
    ACC_INIT
    mainloop<1, 0>(As, Bs,
                   dst + (size_t)b * DD_ * DIM_ + (size_t)m0 * DIM_, DIM_,
                   Qb + (size_t)b * S_ * DIM_ + (size_t)n0 * DIM_, DIM_,
                   DIM_ / 32, acc);
    EPILOGUE_COORDS
    __half* LT = LTb + (size_t)b * DD_ * S_;
#pragma unroll
    for (int i = 0; i < 4; ++i)
#pragma unroll
        for (int j = 0; j < 4; ++j)
#pragma unroll
            for (int r = 0; r < 4; ++r)
                LT[(size_t)(m0 + mrow + i * 16 + q * 4 + r) * S_ +
                   n0 + ncol + j * 16 + col] = __float2half(acc[i][j][r] * SCALE);
}

// ---------------------------------------------------------------------------
// k_pt: PT[e][s] = WvT[e][:] . src[s][:]   (per batch)
// ---------------------------------------------------------------------------
__global__ __launch_bounds__(256) void k_pt(const unsigned short* __restrict__ WvT,
                                            const float* __restrict__ src,
                                            unsigned short* __restrict__ PTb) {
    __shared__ unsigned short As[128 * 32];
    __shared__ unsigned short Bs[128 * 32];
    const int n0 = blockIdx.x * 128, m0 = blockIdx.y * 128, b = blockIdx.z;
    ACC_INIT
    mainloop<0, 1>(As, Bs, WvT + (size_t)m0 * DIM_, DIM_,
                   src + (size_t)b * S_ * DIM_ + (size_t)n0 * DIM_, DIM_,
                   DIM_ / 32, acc);
    EPILOGUE_COORDS
    unsigned short* PT = PTb + (size_t)b * DIM_ * S_;
#pragma unroll
    for (int i = 0; i < 4; ++i)
#pragma unroll
        for (int j = 0; j < 4; ++j)
#pragma unroll
            for (int r = 0; r < 4; ++r)
                PT[(size_t)(m0 + mrow + i * 16 + q * 4 + r) * S_ +
                   n0 + ncol + j * 16 + col] = f2bf(acc[i][j][r]);
}

// ---------------------------------------------------------------------------
// k_dval: partial[ks][b][dd][e] = sum_{s in slice} wT[dd][s] * PT[e][s]
// split-K=2, fp32 partials
// ---------------------------------------------------------------------------
__global__ __launch_bounds__(256) void k_dval(const unsigned short* __restrict__ wTb,
                                              const unsigned short* __restrict__ PTb,
                                              float* __restrict__ Pp) {
    __shared__ unsigned short As[128 * 32];
    __shared__ unsigned short Bs[128 * 32];
    const int n0 = blockIdx.x * 128, m0 = blockIdx.y * 128;
    const int b = blockIdx.z >> 1, ks = blockIdx.z & 1;
    ACC_INIT
    mainloop<0, 0>(As, Bs,
                   wTb + (size_t)b * DD_ * S_ + (size_t)m0 * S_ + ks * 2048, S_,
                   PTb + (size_t)b * DIM_ * S_ + (size_t)n0 * S_ + ks * 2048, S_,
                   2048 / 32, acc);
    EPILOGUE_COORDS
    float* O = Pp + (size_t)ks * B_ * DD_ * DIM_ + (size_t)b * DD_ * DIM_;
#pragma unroll
    for (int i = 0; i < 4; ++i)
#pragma unroll
        for (int j = 0; j < 4; ++j)
#pragma unroll
            for (int r = 0; r < 4; ++r)
                O[(size_t)(m0 + mrow + i * 16 + q * 4 + r) * DIM_ +
                  n0 + ncol + j * 16 + col] = acc[i][j][r];
}

// ---------------------------------------------------------------------------
// k_reduce: d_val = P0 + P1  (4M fp32 elements)
// ---------------------------------------------------------------------------
__global__ __launch_bounds__(256) void k_reduce(const float* __restrict__ Pp,
                                                float* __restrict__ d_val) {
    const size_t idx = ((size_t)blockIdx.x * 256 + threadIdx.x) * 4;
    const size_t half = (size_t)B_ * DD_ * DIM_;
    float4 a = *(const float4*)(Pp + idx);
    float4 b = *(const float4*)(Pp + half + idx);
    float4 o = {a.x + b.x, a.y + b.y, a.z + b.z, a.w + b.w};
    *(float4*)(d_val + idx) = o;
}

// ---------------------------------------------------------------------------
// k_softmax_col: column softmax over LT (dd dim), * softplus(state), in-place
// ---------------------------------------------------------------------------
__global__ __launch_bounds__(256) void k_softmax_col(const float* __restrict__ state,
                                                     void* __restrict__ LTw) {
    __shared__ float Ms[4][64];
    __shared__ float Ls[4][64];
    const int b = blockIdx.y;
    const int s0 = blockIdx.x * 64;
    const int lane = threadIdx.x & 63, wave = threadIdx.x >> 6;
    const int s = s0 + lane;
    const __half* L = (const __half*)LTw + (size_t)b * DD_ * S_ + s;
    unsigned short* W = (unsigned short*)LTw + (size_t)b * DD_ * S_ + s;

    float m = -1e30f, l = 0.f;
    const int dd0 = wave * (DD_ / 4);
#pragma unroll 4
    for (int i = 0; i < DD_ / 4; ++i) {
        float x = __half2float(L[(size_t)(dd0 + i) * S_]);
        float nm = fmaxf(m, x);
        l = l * __expf(m - nm) + __expf(x - nm);
        m = nm;
    }
    Ms[wave][lane] = m;
    Ls[wave][lane] = l;
    __syncthreads();

    float M = fmaxf(fmaxf(Ms[0][lane], Ms[1][lane]), fmaxf(Ms[2][lane], Ms[3][lane]));
    float Ltot = 0.f;
#pragma unroll
    for (int j = 0; j < 4; ++j) Ltot += Ls[j][lane] * __expf(Ms[j][lane] - M);

    const float st = state[(size_t)b * S_ + s];
    const float sp = (st > 15.f) ? st : log1pf(__expf(st));
    const float scale = sp / Ltot;

#pragma unroll 4
    for (int i = 0; i < DD_ / 4; ++i) {
        float x = __half2float(L[(size_t)(dd0 + i) * S_]);
        W[(size_t)(dd0 + i) * S_] = f2bf(__expf(x - M) * scale);
    }
}

// ---------------------------------------------------------------------------
// k_dstate: delta_state[b][dd] = sum_s wT[dd][s] * state[b][s]
// ---------------------------------------------------------------------------
__global__ __launch_bounds__(256) void k_dstate(const unsigned short* __restrict__ wT,
                                                const float* __restrict__ state,
                                                float* __restrict__ out) {
    const int b = blockIdx.y;
    const int dd = blockIdx.x * 4 + (threadIdx.x >> 6);
    const int lane = threadIdx.x & 63;
    const unsigned short* row = wT + (size_t)b * DD_ * S_ + (size_t)dd * S_;
    const float* st = state + (size_t)b * S_;

    float acc = 0.f;
#pragma unroll
    for (int it = 0; it < S_ / 512; ++it) {
        const int s = it * 512 + lane * 8;
        uint4 v = *(const uint4*)(row + s);
        const unsigned short* e = (const unsigned short*)&v;
        float4 f0 = *(const float4*)(st + s);
        float4 f1 = *(const float4*)(st + s + 4);
        acc += bf2f(e[0]) * f0.x + bf2f(e[1]) * f0.y + bf2f(e[2]) * f0.z +
               bf2f(e[3]) * f0.w + bf2f(e[4]) * f1.x + bf2f(e[5]) * f1.y +
               bf2f(e[6]) * f1.z + bf2f(e[7]) * f1.w;
    }
#pragma unroll
    for (int off = 32; off; off >>= 1) acc += __shfl_down(acc, off);
    if (lane == 0) out[(size_t)b * DD_ + dd] = acc;
}

// ---------------------------------------------------------------------------
extern "C" void kernel_launch(void* const* d_in, const int* in_sizes, int n_in,
                              void* d_out, int out_size, void* d_ws, size_t ws_size,
                              hipStream_t stream) {
    const float* src   = (const float*)d_in[0];   // [B,S,DIM]
    const float* state = (const float*)d_in[1];   // [B,S]
    const float* dst   = (const float*)d_in[2];   // [B,D,DIM]
    const float* Wr    = (const float*)d_in[3];   // [DIM,DIM]
    const float* Wv    = (const float*)d_in[4];   // [DIM,DIM]

    // ws layout (128 MiB exactly):
    //   [0,32MB)   Qb [B,S,DIM] bf16 — reused as PT [B,DIM,S] bf16 after k_logitsT
    //   [32,96MB)  LT [B,DD,S]  fp16 — becomes wT bf16 in place after softmax
    //   [96,128MB) Pp: fp32 split-K partials (2 x 16MB); WrT/WvT live in its
    //              first 1MB until k_dval overwrites (consumed by then)
    unsigned short* Qb = (unsigned short*)d_ws;
    unsigned short* PTb = Qb;  // alias — k_pt runs after k_logitsT frees Qb
    unsigned short* LT = Qb + (size_t)B_ * S_ * DIM_;
    float* Pp = (float*)(LT + (size_t)B_ * DD_ * S_);
    unsigned short* WrT = (unsigned short*)Pp;
    unsigned short* WvT = WrT + (size_t)DIM_ * DIM_;

    float* d_state = (float*)d_out;               // [B, DD]
    float* d_val   = (float*)d_out + B_ * DD_;    // [B, DD, DIM]

    k_wt<<<dim3(DIM_ / 64, DIM_ / 64, 2), 256, 0, stream>>>(Wr, Wv, WrT, WvT);
    k_q<<<dim3(DIM_ / 128, (B_ * S_) / 128), 256, 0, stream>>>(src, WrT, Qb);
    k_logitsT<<<dim3(S_ / 128, DD_ / 128, B_), 256, 0, stream>>>(dst, Qb, (__half*)LT);
    k_pt<<<dim3(S_ / 128, DIM_ / 128, B_), 256, 0, stream>>>(WvT, src, PTb);
    k_softmax_col<<<dim3(S_ / 64, B_), 256, 0, stream>>>(state, (void*)LT);
    k_dstate<<<dim3(DD_ / 4, B_), 256, 0, stream>>>(LT, state, d_state);
    k_dval<<<dim3(DIM_ / 128, DD_ / 128, B_ * 2), 256, 0, stream>>>(LT, PTb, Pp);
    k_reduce<<<dim3((B_ * DD_ * DIM_) / 1024), 256, 0, stream>>>(Pp, d_val);
}

// Round 4
// 404.601 us; speedup vs baseline: 1.9801x; 1.0329x over previous
//
#include <hip/hip_runtime.h>
#include <hip/hip_fp16.h>

#define B_   8
#define S_   4096
#define DD_  1024   // dst nodes
#define DIM_ 512
#define SCALE 0.044194173824159216f  // 1/sqrt(512)

typedef __bf16 bf16x8 __attribute__((ext_vector_type(8)));
typedef float  floatx4 __attribute__((ext_vector_type(4)));

__device__ inline unsigned short f2bf(float f) {
    union { float f; unsigned int u; } v; v.f = f;
    unsigned int r = v.u + 0x7fffu + ((v.u >> 16) & 1u);  // RNE
    return (unsigned short)(r >> 16);
}
__device__ inline float bf2f(unsigned short h) {
    union { unsigned int u; float f; } v; v.u = ((unsigned int)h) << 16;
    return v.f;
}
__device__ inline uint4 cvt8(const float* __restrict__ g) {
    float4 f0 = *(const float4*)g;
    float4 f1 = *(const float4*)(g + 4);
    unsigned short tmp[8] = {f2bf(f0.x), f2bf(f0.y), f2bf(f0.z), f2bf(f0.w),
                             f2bf(f1.x), f2bf(f1.y), f2bf(f1.z), f2bf(f1.w)};
    return *(const uint4*)tmp;
}
// async global->LDS, 16B per lane; lds base must be wave-uniform
__device__ inline void async16(unsigned short* lds, const unsigned short* g) {
    __builtin_amdgcn_global_load_lds(
        (const __attribute__((address_space(1))) void*)g,
        (__attribute__((address_space(3))) void*)lds, 16, 0, 0);
}

// ---------------------------------------------------------------------------
// 128x128xK mainloop, BK=32, 256 threads (2x2 waves, each 4x4 MFMA tiles).
// AF32/BF32: 1 = operand is fp32 (stage via cvt8 store), 0 = bf16 (async16).
// LDS layout: [row][32] halfwords, unpadded; flat byte offset = tid*16 per round.
// ---------------------------------------------------------------------------
template <int AF32, int BF32>
__device__ inline void mainloop(unsigned short* As, unsigned short* Bs,
                                const void* Ap, size_t lda,
                                const void* Bp, size_t ldb,
                                int kIters, floatx4 (&acc)[4][4]) {
    const int t = threadIdx.x, lane = t & 63, wave = t >> 6;
    const int rA = t >> 2, cA = (t & 3) * 8;
    const int mrow = (wave >> 1) * 64, ncol = (wave & 1) * 64;
    const int fr = lane & 15, fk = (lane >> 4) * 8;

    const unsigned short* gA16 = nullptr; const float* gA32 = nullptr;
    const unsigned short* gB16 = nullptr; const float* gB32 = nullptr;
    if (AF32) gA32 = (const float*)Ap + (size_t)rA * lda + cA;
    else      gA16 = (const unsigned short*)Ap + (size_t)rA * lda + cA;
    if (BF32) gB32 = (const float*)Bp + (size_t)rA * ldb + cA;
    else      gB16 = (const unsigned short*)Bp + (size_t)rA * ldb + cA;

    unsigned short* ldsA = As + wave * 512;   // halfwords; second 64 rows at +2048
    unsigned short* ldsB = Bs + wave * 512;

    for (int kt = 0; kt < kIters; ++kt) {
        if (AF32) {
            *(uint4*)&As[t * 8]        = cvt8(gA32);
            *(uint4*)&As[2048 + t * 8] = cvt8(gA32 + 64 * lda);
            gA32 += 32;
        } else {
            async16(ldsA,        gA16);
            async16(ldsA + 2048, gA16 + 64 * lda);
            gA16 += 32;
        }
        if (BF32) {
            *(uint4*)&Bs[t * 8]        = cvt8(gB32);
            *(uint4*)&Bs[2048 + t * 8] = cvt8(gB32 + 64 * ldb);
            gB32 += 32;
        } else {
            async16(ldsB,        gB16);
            async16(ldsB + 2048, gB16 + 64 * ldb);
            gB16 += 32;
        }
        __syncthreads();
        bf16x8 af[4], bfr[4];
#pragma unroll
        for (int i = 0; i < 4; ++i)
            af[i] = *(const bf16x8*)&As[(mrow + i * 16 + fr) * 32 + fk];
#pragma unroll
        for (int j = 0; j < 4; ++j)
            bfr[j] = *(const bf16x8*)&Bs[(ncol + j * 16 + fr) * 32 + fk];
#pragma unroll
        for (int i = 0; i < 4; ++i)
#pragma unroll
            for (int j = 0; j < 4; ++j)
                acc[i][j] = __builtin_amdgcn_mfma_f32_16x16x32_bf16(af[i], bfr[j],
                                                                    acc[i][j], 0, 0, 0);
        __syncthreads();
    }
}

#define EPILOGUE_COORDS                                     \
    const int lane = threadIdx.x & 63, wave = threadIdx.x >> 6; \
    const int mrow = (wave >> 1) * 64, ncol = (wave & 1) * 64;  \
    const int col = lane & 15, q = lane >> 4;

#define ACC_INIT                                            \
    floatx4 acc[4][4];                                      \
    _Pragma("unroll") for (int i = 0; i < 4; ++i)           \
        _Pragma("unroll") for (int j = 0; j < 4; ++j)       \
            acc[i][j] = (floatx4){0.f, 0.f, 0.f, 0.f};

// ---------------------------------------------------------------------------
// k_wt: WT[e][d] = W[d][e] * scl, fp32 -> bf16 (SCALE folded into W_route)
// ---------------------------------------------------------------------------
__global__ __launch_bounds__(256) void k_wt(const float* __restrict__ Wr,
                                            const float* __restrict__ Wv,
                                            unsigned short* __restrict__ WrT,
                                            unsigned short* __restrict__ WvT) {
    __shared__ float Ts[64 * 68];
    const float* W = blockIdx.z ? Wv : Wr;
    unsigned short* WT = blockIdx.z ? WvT : WrT;
    const float scl = blockIdx.z ? 1.f : SCALE;
    const int d0 = blockIdx.x * 64, e0 = blockIdx.y * 64;
    const int t = threadIdx.x;
    {
        const int r = t >> 2, c0 = (t & 3) * 16;
        const float* g = W + (size_t)(d0 + r) * DIM_ + e0 + c0;
#pragma unroll
        for (int i = 0; i < 4; ++i)
            *(float4*)&Ts[r * 68 + c0 + i * 4] = *(const float4*)(g + i * 4);
    }
    __syncthreads();
    {
        const int rr = t >> 2, c0 = (t & 3) * 16;
        unsigned short tmp[16];
#pragma unroll
        for (int j = 0; j < 16; ++j) tmp[j] = f2bf(Ts[(c0 + j) * 68 + rr] * scl);
        unsigned short* o = WT + (size_t)(e0 + rr) * DIM_ + d0 + c0;
        *(uint4*)o = *(const uint4*)tmp;
        *(uint4*)(o + 8) = *(const uint4*)(tmp + 8);
    }
}

// ---------------------------------------------------------------------------
// k_dc: dst fp32 -> bf16 (flat copy-convert, 4M elements)
// ---------------------------------------------------------------------------
__global__ __launch_bounds__(256) void k_dc(const float* __restrict__ dst,
                                            unsigned short* __restrict__ dstb) {
    const size_t idx = ((size_t)blockIdx.x * 256 + threadIdx.x) * 8;
    *(uint4*)&dstb[idx] = cvt8(dst + idx);
}

// ---------------------------------------------------------------------------
// k_q: Q[s][e] = src[s][:] . WrT[e][:]   (SCALE pre-folded into WrT)
// ---------------------------------------------------------------------------
__global__ __launch_bounds__(256) void k_q(const float* __restrict__ src,
                                           const unsigned short* __restrict__ WrT,
                                           unsigned short* __restrict__ Qb) {
    __shared__ unsigned short As[128 * 32];
    __shared__ unsigned short Bs[128 * 32];
    const int n0 = blockIdx.x * 128, m0 = blockIdx.y * 128;
    ACC_INIT
    mainloop<1, 0>(As, Bs, src + (size_t)m0 * DIM_, DIM_,
                   WrT + (size_t)n0 * DIM_, DIM_, DIM_ / 32, acc);
    EPILOGUE_COORDS
#pragma unroll
    for (int i = 0; i < 4; ++i)
#pragma unroll
        for (int j = 0; j < 4; ++j)
#pragma unroll
            for (int r = 0; r < 4; ++r)
                Qb[(size_t)(m0 + mrow + i * 16 + q * 4 + r) * DIM_ +
                   n0 + ncol + j * 16 + col] = f2bf(acc[i][j][r]);
}

// ---------------------------------------------------------------------------
// k_logitsT: LT[dd][s] = dstb[dd][:] . Q[s][:]  -> fp16 (per batch)
// both operands bf16 -> pure async16 staging
// ---------------------------------------------------------------------------
__global__ __launch_bounds__(256) void k_logitsT(const unsigned short* __restrict__ dstb,
                                                 const unsigned short* __restrict__ Qb,
                                                 __half* __restrict__ LTb) {
    __shared__ unsigned short As[128 * 32];
    __shared__ unsigned short Bs[128 * 32];
    const int n0 = blockIdx.x * 128, m0 = blockIdx.y * 128, b = blockIdx.z;
    ACC_INIT
    mainloop<0, 0>(As, Bs,
                   dstb + (size_t)b * DD_ * DIM_ + (size_t)m0 * DIM_, DIM_,
                   Qb + (size_t)b * S_ * DIM_ + (size_t)n0 * DIM_, DIM_,
                   DIM_ / 32, acc);
    EPILOGUE_COORDS
    __half* LT = LTb + (size_t)b * DD_ * S_;
#pragma unroll
    for (int i = 0; i < 4; ++i)
#pragma unroll
        for (int j = 0; j < 4; ++j)
#pragma unroll
            for (int r = 0; r < 4; ++r)
                LT[(size_t)(m0 + mrow + i * 16 + q * 4 + r) * S_ +
                   n0 + ncol + j * 16 + col] = __float2half(acc[i][j][r]);
}

// ---------------------------------------------------------------------------
// k_pt: PT[e][s] = WvT[e][:] . src[s][:]   (per batch)
// ---------------------------------------------------------------------------
__global__ __launch_bounds__(256) void k_pt(const unsigned short* __restrict__ WvT,
                                            const float* __restrict__ src,
                                            unsigned short* __restrict__ PTb) {
    __shared__ unsigned short As[128 * 32];
    __shared__ unsigned short Bs[128 * 32];
    const int n0 = blockIdx.x * 128, m0 = blockIdx.y * 128, b = blockIdx.z;
    ACC_INIT
    mainloop<0, 1>(As, Bs, WvT + (size_t)m0 * DIM_, DIM_,
                   src + (size_t)b * S_ * DIM_ + (size_t)n0 * DIM_, DIM_,
                   DIM_ / 32, acc);
    EPILOGUE_COORDS
    unsigned short* PT = PTb + (size_t)b * DIM_ * S_;
#pragma unroll
    for (int i = 0; i < 4; ++i)
#pragma unroll
        for (int j = 0; j < 4; ++j)
#pragma unroll
            for (int r = 0; r < 4; ++r)
                PT[(size_t)(m0 + mrow + i * 16 + q * 4 + r) * S_ +
                   n0 + ncol + j * 16 + col] = f2bf(acc[i][j][r]);
}

// ---------------------------------------------------------------------------
// k_dval: partial[ks][b][dd][e] = sum_{s slice ks} wT[dd][s]*PT[e][s], fp16 out
// split-K = 4
// ---------------------------------------------------------------------------
__global__ __launch_bounds__(256) void k_dval(const unsigned short* __restrict__ wTb,
                                              const unsigned short* __restrict__ PTb,
                                              __half* __restrict__ Pp) {
    __shared__ unsigned short As[128 * 32];
    __shared__ unsigned short Bs[128 * 32];
    const int n0 = blockIdx.x * 128, m0 = blockIdx.y * 128;
    const int b = blockIdx.z >> 2, ks = blockIdx.z & 3;
    ACC_INIT
    mainloop<0, 0>(As, Bs,
                   wTb + (size_t)b * DD_ * S_ + (size_t)m0 * S_ + ks * 1024, S_,
                   PTb + (size_t)b * DIM_ * S_ + (size_t)n0 * S_ + ks * 1024, S_,
                   1024 / 32, acc);
    EPILOGUE_COORDS
    __half* O = Pp + (size_t)ks * B_ * DD_ * DIM_ + (size_t)b * DD_ * DIM_;
#pragma unroll
    for (int i = 0; i < 4; ++i)
#pragma unroll
        for (int j = 0; j < 4; ++j)
#pragma unroll
            for (int r = 0; r < 4; ++r)
                O[(size_t)(m0 + mrow + i * 16 + q * 4 + r) * DIM_ +
                  n0 + ncol + j * 16 + col] = __float2half(acc[i][j][r]);
}

// ---------------------------------------------------------------------------
// k_reduce: d_val = sum of 4 fp16 partial slices
// ---------------------------------------------------------------------------
__global__ __launch_bounds__(256) void k_reduce(const __half* __restrict__ Pp,
                                                float* __restrict__ d_val) {
    const size_t idx = ((size_t)blockIdx.x * 256 + threadIdx.x) * 8;
    const size_t n = (size_t)B_ * DD_ * DIM_;
    float o[8] = {0.f, 0.f, 0.f, 0.f, 0.f, 0.f, 0.f, 0.f};
#pragma unroll
    for (int ks = 0; ks < 4; ++ks) {
        uint4 v = *(const uint4*)(Pp + (size_t)ks * n + idx);
        const __half* h = (const __half*)&v;
#pragma unroll
        for (int j = 0; j < 8; ++j) o[j] += __half2float(h[j]);
    }
    *(float4*)(d_val + idx)     = (float4){o[0], o[1], o[2], o[3]};
    *(float4*)(d_val + idx + 4) = (float4){o[4], o[5], o[6], o[7]};
}

// ---------------------------------------------------------------------------
// k_softmax_col: column softmax over LT (dd dim), * softplus(state), in-place
// ---------------------------------------------------------------------------
__global__ __launch_bounds__(256) void k_softmax_col(const float* __restrict__ state,
                                                     void* __restrict__ LTw) {
    __shared__ float Ms[4][64];
    __shared__ float Ls[4][64];
    const int b = blockIdx.y;
    const int s0 = blockIdx.x * 64;
    const int lane = threadIdx.x & 63, wave = threadIdx.x >> 6;
    const int s = s0 + lane;
    const __half* L = (const __half*)LTw + (size_t)b * DD_ * S_ + s;
    unsigned short* W = (unsigned short*)LTw + (size_t)b * DD_ * S_ + s;

    float m = -1e30f, l = 0.f;
    const int dd0 = wave * (DD_ / 4);
#pragma unroll 4
    for (int i = 0; i < DD_ / 4; ++i) {
        float x = __half2float(L[(size_t)(dd0 + i) * S_]);
        float nm = fmaxf(m, x);
        l = l * __expf(m - nm) + __expf(x - nm);
        m = nm;
    }
    Ms[wave][lane] = m;
    Ls[wave][lane] = l;
    __syncthreads();

    float M = fmaxf(fmaxf(Ms[0][lane], Ms[1][lane]), fmaxf(Ms[2][lane], Ms[3][lane]));
    float Ltot = 0.f;
#pragma unroll
    for (int j = 0; j < 4; ++j) Ltot += Ls[j][lane] * __expf(Ms[j][lane] - M);

    const float st = state[(size_t)b * S_ + s];
    const float sp = (st > 15.f) ? st : log1pf(__expf(st));
    const float scale = sp / Ltot;

#pragma unroll 4
    for (int i = 0; i < DD_ / 4; ++i) {
        float x = __half2float(L[(size_t)(dd0 + i) * S_]);
        W[(size_t)(dd0 + i) * S_] = f2bf(__expf(x - M) * scale);
    }
}

// ---------------------------------------------------------------------------
// k_dstate: delta_state[b][dd] = sum_s wT[dd][s] * state[b][s]
// ---------------------------------------------------------------------------
__global__ __launch_bounds__(256) void k_dstate(const unsigned short* __restrict__ wT,
                                                const float* __restrict__ state,
                                                float* __restrict__ out) {
    const int b = blockIdx.y;
    const int dd = blockIdx.x * 4 + (threadIdx.x >> 6);
    const int lane = threadIdx.x & 63;
    const unsigned short* row = wT + (size_t)b * DD_ * S_ + (size_t)dd * S_;
    const float* st = state + (size_t)b * S_;

    float acc = 0.f;
#pragma unroll
    for (int it = 0; it < S_ / 512; ++it) {
        const int s = it * 512 + lane * 8;
        uint4 v = *(const uint4*)(row + s);
        const unsigned short* e = (const unsigned short*)&v;
        float4 f0 = *(const float4*)(st + s);
        float4 f1 = *(const float4*)(st + s + 4);
        acc += bf2f(e[0]) * f0.x + bf2f(e[1]) * f0.y + bf2f(e[2]) * f0.z +
               bf2f(e[3]) * f0.w + bf2f(e[4]) * f1.x + bf2f(e[5]) * f1.y +
               bf2f(e[6]) * f1.z + bf2f(e[7]) * f1.w;
    }
#pragma unroll
    for (int off = 32; off; off >>= 1) acc += __shfl_down(acc, off);
    if (lane == 0) out[(size_t)b * DD_ + dd] = acc;
}

// ---------------------------------------------------------------------------
extern "C" void kernel_launch(void* const* d_in, const int* in_sizes, int n_in,
                              void* d_out, int out_size, void* d_ws, size_t ws_size,
                              hipStream_t stream) {
    const float* src   = (const float*)d_in[0];   // [B,S,DIM]
    const float* state = (const float*)d_in[1];   // [B,S]
    const float* dst   = (const float*)d_in[2];   // [B,D,DIM]
    const float* Wr    = (const float*)d_in[3];   // [DIM,DIM]
    const float* Wv    = (const float*)d_in[4];   // [DIM,DIM]

    // ws layout (128 MiB):
    //  R0 [0,32MB)   Qb [B,S,DIM] bf16 — aliased as PT [B,DIM,S] after k_logitsT
    //  R1 [32,96MB)  LT [B,DD,S]  fp16 — becomes wT bf16 in place after softmax
    //  R2 [96,128MB) first: WrT(0.5) WvT(0.5) dstb(8); later: Pp fp16 4x8MB
    //                (all R2 readers finish before k_dval writes Pp)
    unsigned short* Qb  = (unsigned short*)d_ws;
    unsigned short* PTb = Qb;  // alias — k_pt runs after k_logitsT frees Qb
    unsigned short* LT  = Qb + (size_t)B_ * S_ * DIM_;
    unsigned short* R2  = LT + (size_t)B_ * DD_ * S_;
    unsigned short* WrT = R2;
    unsigned short* WvT = WrT + (size_t)DIM_ * DIM_;
    unsigned short* dstb = WvT + (size_t)DIM_ * DIM_;
    __half* Pp = (__half*)R2;

    float* d_state = (float*)d_out;               // [B, DD]
    float* d_val   = (float*)d_out + B_ * DD_;    // [B, DD, DIM]

    k_wt<<<dim3(DIM_ / 64, DIM_ / 64, 2), 256, 0, stream>>>(Wr, Wv, WrT, WvT);
    k_dc<<<dim3((B_ * DD_ * DIM_) / 2048), 256, 0, stream>>>(dst, dstb);
    k_q<<<dim3(DIM_ / 128, (B_ * S_) / 128), 256, 0, stream>>>(src, WrT, Qb);
    k_logitsT<<<dim3(S_ / 128, DD_ / 128, B_), 256, 0, stream>>>(dstb, Qb, (__half*)LT);
    k_pt<<<dim3(S_ / 128, DIM_ / 128, B_), 256, 0, stream>>>(WvT, src, PTb);
    k_softmax_col<<<dim3(S_ / 64, B_), 256, 0, stream>>>(state, (void*)LT);
    k_dstate<<<dim3(DD_ / 4, B_), 256, 0, stream>>>(LT, state, d_state);
    k_dval<<<dim3(DIM_ / 128, DD_ / 128, B_ * 4), 256, 0, stream>>>(LT, PTb, Pp);
    k_reduce<<<dim3((B_ * DD_ * DIM_) / 2048), 256, 0, stream>>>(Pp, d_val);
}

// Round 5
// 353.760 us; speedup vs baseline: 2.2646x; 1.1437x over previous
//
#include <hip/hip_runtime.h>
#include <hip/hip_fp16.h>

#define B_   8
#define S_   4096
#define DD_  1024   // dst nodes
#define DIM_ 512
#define SCALE 0.044194173824159216f  // 1/sqrt(512)

typedef __bf16 bf16x8 __attribute__((ext_vector_type(8)));
typedef float  floatx4 __attribute__((ext_vector_type(4)));

__device__ inline unsigned short f2bf(float f) {
    union { float f; unsigned int u; } v; v.f = f;
    unsigned int r = v.u + 0x7fffu + ((v.u >> 16) & 1u);  // RNE
    return (unsigned short)(r >> 16);
}
__device__ inline float bf2f(unsigned short h) {
    union { unsigned int u; float f; } v; v.u = ((unsigned int)h) << 16;
    return v.f;
}
__device__ inline uint4 cvt8(const float* __restrict__ g) {
    float4 f0 = *(const float4*)g;
    float4 f1 = *(const float4*)(g + 4);
    unsigned short tmp[8] = {f2bf(f0.x), f2bf(f0.y), f2bf(f0.z), f2bf(f0.w),
                             f2bf(f1.x), f2bf(f1.y), f2bf(f1.z), f2bf(f1.w)};
    return *(const uint4*)tmp;
}
// async global->LDS, 16B per lane; lds base must be wave-uniform
__device__ inline void async16(unsigned short* lds, const unsigned short* g) {
    __builtin_amdgcn_global_load_lds(
        (const __attribute__((address_space(1))) void*)g,
        (__attribute__((address_space(3))) void*)lds, 16, 0, 0);
}

// ---------------------------------------------------------------------------
// 128x128xK mainloop, BK=32, 256 threads (2x2 waves, each 4x4 MFMA tiles).
// AF32/BF32: 1 = operand is fp32 (stage via cvt8 store), 0 = bf16 (async16).
// ---------------------------------------------------------------------------
template <int AF32, int BF32>
__device__ inline void mainloop(unsigned short* As, unsigned short* Bs,
                                const void* Ap, size_t lda,
                                const void* Bp, size_t ldb,
                                int kIters, floatx4 (&acc)[4][4]) {
    const int t = threadIdx.x, lane = t & 63, wave = t >> 6;
    const int rA = t >> 2, cA = (t & 3) * 8;
    const int mrow = (wave >> 1) * 64, ncol = (wave & 1) * 64;
    const int fr = lane & 15, fk = (lane >> 4) * 8;

    const unsigned short* gA16 = nullptr; const float* gA32 = nullptr;
    const unsigned short* gB16 = nullptr; const float* gB32 = nullptr;
    if (AF32) gA32 = (const float*)Ap + (size_t)rA * lda + cA;
    else      gA16 = (const unsigned short*)Ap + (size_t)rA * lda + cA;
    if (BF32) gB32 = (const float*)Bp + (size_t)rA * ldb + cA;
    else      gB16 = (const unsigned short*)Bp + (size_t)rA * ldb + cA;

    unsigned short* ldsA = As + wave * 512;   // halfwords; second 64 rows at +2048
    unsigned short* ldsB = Bs + wave * 512;

    for (int kt = 0; kt < kIters; ++kt) {
        if (AF32) {
            *(uint4*)&As[t * 8]        = cvt8(gA32);
            *(uint4*)&As[2048 + t * 8] = cvt8(gA32 + 64 * lda);
            gA32 += 32;
        } else {
            async16(ldsA,        gA16);
            async16(ldsA + 2048, gA16 + 64 * lda);
            gA16 += 32;
        }
        if (BF32) {
            *(uint4*)&Bs[t * 8]        = cvt8(gB32);
            *(uint4*)&Bs[2048 + t * 8] = cvt8(gB32 + 64 * ldb);
            gB32 += 32;
        } else {
            async16(ldsB,        gB16);
            async16(ldsB + 2048, gB16 + 64 * ldb);
            gB16 += 32;
        }
        __syncthreads();
        bf16x8 af[4], bfr[4];
#pragma unroll
        for (int i = 0; i < 4; ++i)
            af[i] = *(const bf16x8*)&As[(mrow + i * 16 + fr) * 32 + fk];
#pragma unroll
        for (int j = 0; j < 4; ++j)
            bfr[j] = *(const bf16x8*)&Bs[(ncol + j * 16 + fr) * 32 + fk];
#pragma unroll
        for (int i = 0; i < 4; ++i)
#pragma unroll
            for (int j = 0; j < 4; ++j)
                acc[i][j] = __builtin_amdgcn_mfma_f32_16x16x32_bf16(af[i], bfr[j],
                                                                    acc[i][j], 0, 0, 0);
        __syncthreads();
    }
}

#define EPILOGUE_COORDS                                     \
    const int lane = threadIdx.x & 63, wave = threadIdx.x >> 6; \
    const int mrow = (wave >> 1) * 64, ncol = (wave & 1) * 64;  \
    const int col = lane & 15, q = lane >> 4;

#define ACC_INIT                                            \
    floatx4 acc[4][4];                                      \
    _Pragma("unroll") for (int i = 0; i < 4; ++i)           \
        _Pragma("unroll") for (int j = 0; j < 4; ++j)       \
            acc[i][j] = (floatx4){0.f, 0.f, 0.f, 0.f};

// ---------------------------------------------------------------------------
// k_wt: WT[e][d] = W[d][e] * scl, fp32 -> bf16 (SCALE folded into W_route)
// ---------------------------------------------------------------------------
__global__ __launch_bounds__(256) void k_wt(const float* __restrict__ Wr,
                                            const float* __restrict__ Wv,
                                            unsigned short* __restrict__ WrT,
                                            unsigned short* __restrict__ WvT) {
    __shared__ float Ts[64 * 68];
    const float* W = blockIdx.z ? Wv : Wr;
    unsigned short* WT = blockIdx.z ? WvT : WrT;
    const float scl = blockIdx.z ? 1.f : SCALE;
    const int d0 = blockIdx.x * 64, e0 = blockIdx.y * 64;
    const int t = threadIdx.x;
    {
        const int r = t >> 2, c0 = (t & 3) * 16;
        const float* g = W + (size_t)(d0 + r) * DIM_ + e0 + c0;
#pragma unroll
        for (int i = 0; i < 4; ++i)
            *(float4*)&Ts[r * 68 + c0 + i * 4] = *(const float4*)(g + i * 4);
    }
    __syncthreads();
    {
        const int rr = t >> 2, c0 = (t & 3) * 16;
        unsigned short tmp[16];
#pragma unroll
        for (int j = 0; j < 16; ++j) tmp[j] = f2bf(Ts[(c0 + j) * 68 + rr] * scl);
        unsigned short* o = WT + (size_t)(e0 + rr) * DIM_ + d0 + c0;
        *(uint4*)o = *(const uint4*)tmp;
        *(uint4*)(o + 8) = *(const uint4*)(tmp + 8);
    }
}

// ---------------------------------------------------------------------------
// k_dc: dst fp32 -> bf16 (flat copy-convert, 4M elements)
// ---------------------------------------------------------------------------
__global__ __launch_bounds__(256) void k_dc(const float* __restrict__ dst,
                                            unsigned short* __restrict__ dstb) {
    const size_t idx = ((size_t)blockIdx.x * 256 + threadIdx.x) * 8;
    *(uint4*)&dstb[idx] = cvt8(dst + idx);
}

// ---------------------------------------------------------------------------
// k_q: Q[s][e] = src[s][:] . WrT[e][:]   (SCALE pre-folded into WrT)
// ---------------------------------------------------------------------------
__global__ __launch_bounds__(256) void k_q(const float* __restrict__ src,
                                           const unsigned short* __restrict__ WrT,
                                           unsigned short* __restrict__ Qb) {
    __shared__ unsigned short As[128 * 32];
    __shared__ unsigned short Bs[128 * 32];
    const int n0 = blockIdx.x * 128, m0 = blockIdx.y * 128;
    ACC_INIT
    mainloop<1, 0>(As, Bs, src + (size_t)m0 * DIM_, DIM_,
                   WrT + (size_t)n0 * DIM_, DIM_, DIM_ / 32, acc);
    EPILOGUE_COORDS
#pragma unroll
    for (int i = 0; i < 4; ++i)
#pragma unroll
        for (int j = 0; j < 4; ++j)
#pragma unroll
            for (int r = 0; r < 4; ++r)
                Qb[(size_t)(m0 + mrow + i * 16 + q * 4 + r) * DIM_ +
                   n0 + ncol + j * 16 + col] = f2bf(acc[i][j][r]);
}

// ---------------------------------------------------------------------------
// k_logitsT: LT[dd][s] = exp(dstb[dd][:] . Q[s][:]) -> bf16  (per batch)
// epilogue also writes per-(b, dd-tile) column sums Lpart[b][tile][s] (fp32).
// Logits are O(1) by construction (unit-variance) -> exp without max-sub is safe.
// ---------------------------------------------------------------------------
__global__ __launch_bounds__(256) void k_logitsT(const unsigned short* __restrict__ dstb,
                                                 const unsigned short* __restrict__ Qb,
                                                 unsigned short* __restrict__ LTb,
                                                 float* __restrict__ Lpart) {
    __shared__ unsigned short As[128 * 32];
    __shared__ unsigned short Bs[128 * 32];
    __shared__ float csum[8][128];
    const int n0 = blockIdx.x * 128, m0 = blockIdx.y * 128, b = blockIdx.z;
    ACC_INIT
    mainloop<0, 0>(As, Bs,
                   dstb + (size_t)b * DD_ * DIM_ + (size_t)m0 * DIM_, DIM_,
                   Qb + (size_t)b * S_ * DIM_ + (size_t)n0 * DIM_, DIM_,
                   DIM_ / 32, acc);
    EPILOGUE_COORDS
    unsigned short* LT = LTb + (size_t)b * DD_ * S_;
    float psum[4] = {0.f, 0.f, 0.f, 0.f};
#pragma unroll
    for (int i = 0; i < 4; ++i)
#pragma unroll
        for (int j = 0; j < 4; ++j)
#pragma unroll
            for (int r = 0; r < 4; ++r) {
                float e = __expf(acc[i][j][r]);
                LT[(size_t)(m0 + mrow + i * 16 + q * 4 + r) * S_ +
                   n0 + ncol + j * 16 + col] = f2bf(e);
                psum[j] += e;
            }
    const int slice = (wave >> 1) * 4 + q;
#pragma unroll
    for (int j = 0; j < 4; ++j) csum[slice][ncol + j * 16 + col] = psum[j];
    __syncthreads();
    const int t = threadIdx.x;
    if (t < 128) {
        float v = 0.f;
#pragma unroll
        for (int k = 0; k < 8; ++k) v += csum[k][t];
        Lpart[((size_t)b * 8 + blockIdx.y) * S_ + n0 + t] = v;
    }
}

// ---------------------------------------------------------------------------
// k_finalize: scale[b][s] = softplus(state[b][s]) / sum_tiles Lpart
// ---------------------------------------------------------------------------
__global__ __launch_bounds__(256) void k_finalize(const float* __restrict__ state,
                                                  const float* __restrict__ Lpart,
                                                  float* __restrict__ scale) {
    const int i = blockIdx.x * 256 + threadIdx.x;    // flat b*S+s
    const int b = i >> 12, s = i & (S_ - 1);
    float d = 0.f;
#pragma unroll
    for (int k = 0; k < 8; ++k) d += Lpart[((size_t)b * 8 + k) * S_ + s];
    const float st = state[i];
    const float sp = (st > 15.f) ? st : log1pf(__expf(st));
    scale[i] = sp / d;
}

// ---------------------------------------------------------------------------
// k_pt: PT[e][s] = (WvT[e][:] . src[s][:]) * scale[b][s]   (per batch)
// scale folded here so k_dval needs no per-element softmax normalization
// ---------------------------------------------------------------------------
__global__ __launch_bounds__(256) void k_pt(const unsigned short* __restrict__ WvT,
                                            const float* __restrict__ src,
                                            const float* __restrict__ scale,
                                            unsigned short* __restrict__ PTb) {
    __shared__ unsigned short As[128 * 32];
    __shared__ unsigned short Bs[128 * 32];
    const int n0 = blockIdx.x * 128, m0 = blockIdx.y * 128, b = blockIdx.z;
    ACC_INIT
    mainloop<0, 1>(As, Bs, WvT + (size_t)m0 * DIM_, DIM_,
                   src + (size_t)b * S_ * DIM_ + (size_t)n0 * DIM_, DIM_,
                   DIM_ / 32, acc);
    EPILOGUE_COORDS
    unsigned short* PT = PTb + (size_t)b * DIM_ * S_;
    const float* sc = scale + (size_t)b * S_;
#pragma unroll
    for (int j = 0; j < 4; ++j) {
        const float scj = sc[n0 + ncol + j * 16 + col];
#pragma unroll
        for (int i = 0; i < 4; ++i)
#pragma unroll
            for (int r = 0; r < 4; ++r)
                PT[(size_t)(m0 + mrow + i * 16 + q * 4 + r) * S_ +
                   n0 + ncol + j * 16 + col] = f2bf(acc[i][j][r] * scj);
    }
}

// ---------------------------------------------------------------------------
// k_dval: partial[ks][b][dd][e] = sum_{s slice} LT[dd][s]*PT[e][s], fp16 out
// (softmax normalization pre-folded into PT)
// ---------------------------------------------------------------------------
__global__ __launch_bounds__(256) void k_dval(const unsigned short* __restrict__ LTb,
                                              const unsigned short* __restrict__ PTb,
                                              __half* __restrict__ Pp) {
    __shared__ unsigned short As[128 * 32];
    __shared__ unsigned short Bs[128 * 32];
    const int n0 = blockIdx.x * 128, m0 = blockIdx.y * 128;
    const int b = blockIdx.z >> 2, ks = blockIdx.z & 3;
    ACC_INIT
    mainloop<0, 0>(As, Bs,
                   LTb + (size_t)b * DD_ * S_ + (size_t)m0 * S_ + ks * 1024, S_,
                   PTb + (size_t)b * DIM_ * S_ + (size_t)n0 * S_ + ks * 1024, S_,
                   1024 / 32, acc);
    EPILOGUE_COORDS
    __half* O = Pp + (size_t)ks * B_ * DD_ * DIM_ + (size_t)b * DD_ * DIM_;
#pragma unroll
    for (int i = 0; i < 4; ++i)
#pragma unroll
        for (int j = 0; j < 4; ++j)
#pragma unroll
            for (int r = 0; r < 4; ++r)
                O[(size_t)(m0 + mrow + i * 16 + q * 4 + r) * DIM_ +
                  n0 + ncol + j * 16 + col] = __float2half(acc[i][j][r]);
}

// ---------------------------------------------------------------------------
// k_reduce: d_val = sum of 4 fp16 partial slices
// ---------------------------------------------------------------------------
__global__ __launch_bounds__(256) void k_reduce(const __half* __restrict__ Pp,
                                                float* __restrict__ d_val) {
    const size_t idx = ((size_t)blockIdx.x * 256 + threadIdx.x) * 8;
    const size_t n = (size_t)B_ * DD_ * DIM_;
    float o[8] = {0.f, 0.f, 0.f, 0.f, 0.f, 0.f, 0.f, 0.f};
#pragma unroll
    for (int ks = 0; ks < 4; ++ks) {
        uint4 v = *(const uint4*)(Pp + (size_t)ks * n + idx);
        const __half* h = (const __half*)&v;
#pragma unroll
        for (int j = 0; j < 8; ++j) o[j] += __half2float(h[j]);
    }
    *(float4*)(d_val + idx)     = (float4){o[0], o[1], o[2], o[3]};
    *(float4*)(d_val + idx + 4) = (float4){o[4], o[5], o[6], o[7]};
}

// ---------------------------------------------------------------------------
// k_dstate: delta_state[b][dd] = sum_s LT[dd][s] * scale[b][s] * state[b][s]
// ---------------------------------------------------------------------------
__global__ __launch_bounds__(256) void k_dstate(const unsigned short* __restrict__ LT,
                                                const float* __restrict__ state,
                                                const float* __restrict__ scale,
                                                float* __restrict__ out) {
    const int b = blockIdx.y;
    const int dd = blockIdx.x * 4 + (threadIdx.x >> 6);
    const int lane = threadIdx.x & 63;
    const unsigned short* row = LT + (size_t)b * DD_ * S_ + (size_t)dd * S_;
    const float* st = state + (size_t)b * S_;
    const float* sc = scale + (size_t)b * S_;

    float acc = 0.f;
#pragma unroll
    for (int it = 0; it < S_ / 512; ++it) {
        const int s = it * 512 + lane * 8;
        uint4 v = *(const uint4*)(row + s);
        const unsigned short* e = (const unsigned short*)&v;
        float4 f0 = *(const float4*)(st + s);
        float4 f1 = *(const float4*)(st + s + 4);
        float4 c0 = *(const float4*)(sc + s);
        float4 c1 = *(const float4*)(sc + s + 4);
        acc += bf2f(e[0]) * f0.x * c0.x + bf2f(e[1]) * f0.y * c0.y +
               bf2f(e[2]) * f0.z * c0.z + bf2f(e[3]) * f0.w * c0.w +
               bf2f(e[4]) * f1.x * c1.x + bf2f(e[5]) * f1.y * c1.y +
               bf2f(e[6]) * f1.z * c1.z + bf2f(e[7]) * f1.w * c1.w;
    }
#pragma unroll
    for (int off = 32; off; off >>= 1) acc += __shfl_down(acc, off);
    if (lane == 0) out[(size_t)b * DD_ + dd] = acc;
}

// ---------------------------------------------------------------------------
extern "C" void kernel_launch(void* const* d_in, const int* in_sizes, int n_in,
                              void* d_out, int out_size, void* d_ws, size_t ws_size,
                              hipStream_t stream) {
    const float* src   = (const float*)d_in[0];   // [B,S,DIM]
    const float* state = (const float*)d_in[1];   // [B,S]
    const float* dst   = (const float*)d_in[2];   // [B,D,DIM]
    const float* Wr    = (const float*)d_in[3];   // [DIM,DIM]
    const float* Wv    = (const float*)d_in[4];   // [DIM,DIM]

    // ws layout (128 MiB):
    //  R0 [0,32MB)   Qb [B,S,DIM] bf16 — aliased as PT [B,DIM,S] after k_logitsT
    //  R1 [32,96MB)  LT [B,DD,S]  bf16 exp(logit) — written once, read twice
    //  R2 [96,128MB) early: WrT(.5) WvT(.5) dstb(8) Lpart(1) scale(.125)
    //                late:  Pp fp16 4x8MB (k_dval) — all early readers done by then
    unsigned short* Qb  = (unsigned short*)d_ws;
    unsigned short* PTb = Qb;  // alias — k_pt runs after k_logitsT frees Qb
    unsigned short* LT  = Qb + (size_t)B_ * S_ * DIM_;
    unsigned short* R2  = LT + (size_t)B_ * DD_ * S_;
    unsigned short* WrT = R2;
    unsigned short* WvT = WrT + (size_t)DIM_ * DIM_;
    unsigned short* dstb = WvT + (size_t)DIM_ * DIM_;
    float* Lpart = (float*)(dstb + (size_t)B_ * DD_ * DIM_);  // [B][8][S]
    float* scale = Lpart + (size_t)B_ * 8 * S_;               // [B][S]
    __half* Pp = (__half*)R2;

    float* d_state = (float*)d_out;               // [B, DD]
    float* d_val   = (float*)d_out + B_ * DD_;    // [B, DD, DIM]

    k_wt<<<dim3(DIM_ / 64, DIM_ / 64, 2), 256, 0, stream>>>(Wr, Wv, WrT, WvT);
    k_dc<<<dim3((B_ * DD_ * DIM_) / 2048), 256, 0, stream>>>(dst, dstb);
    k_q<<<dim3(DIM_ / 128, (B_ * S_) / 128), 256, 0, stream>>>(src, WrT, Qb);
    k_logitsT<<<dim3(S_ / 128, DD_ / 128, B_), 256, 0, stream>>>(dstb, Qb, LT, Lpart);
    k_finalize<<<dim3((B_ * S_) / 256), 256, 0, stream>>>(state, Lpart, scale);
    k_pt<<<dim3(S_ / 128, DIM_ / 128, B_), 256, 0, stream>>>(WvT, src, scale, PTb);
    k_dstate<<<dim3(DD_ / 4, B_), 256, 0, stream>>>(LT, state, scale, d_state);
    k_dval<<<dim3(DIM_ / 128, DD_ / 128, B_ * 4), 256, 0, stream>>>(LT, PTb, Pp);
    k_reduce<<<dim3((B_ * DD_ * DIM_) / 2048), 256, 0, stream>>>(Pp, d_val);
}

// Round 6
// 322.283 us; speedup vs baseline: 2.4858x; 1.0977x over previous
//
#include <hip/hip_runtime.h>
#include <hip/hip_fp16.h>

#define B_   8
#define S_   4096
#define DD_  1024   // dst nodes
#define DIM_ 512
#define SCALE 0.044194173824159216f  // 1/sqrt(512)

typedef __bf16 bf16x8 __attribute__((ext_vector_type(8)));
typedef float  floatx4 __attribute__((ext_vector_type(4)));

__device__ inline unsigned short f2bf(float f) {
    union { float f; unsigned int u; } v; v.f = f;
    unsigned int r = v.u + 0x7fffu + ((v.u >> 16) & 1u);  // RNE
    return (unsigned short)(r >> 16);
}
__device__ inline float bf2f(unsigned short h) {
    union { unsigned int u; float f; } v; v.u = ((unsigned int)h) << 16;
    return v.f;
}
__device__ inline uint4 cvt8(const float* __restrict__ g) {
    float4 f0 = *(const float4*)g;
    float4 f1 = *(const float4*)(g + 4);
    unsigned short tmp[8] = {f2bf(f0.x), f2bf(f0.y), f2bf(f0.z), f2bf(f0.w),
                             f2bf(f1.x), f2bf(f1.y), f2bf(f1.z), f2bf(f1.w)};
    return *(const uint4*)tmp;
}
// async global->LDS, 16B per lane; lds base must be wave-uniform
__device__ inline void async16(unsigned short* lds, const unsigned short* g) {
    __builtin_amdgcn_global_load_lds(
        (const __attribute__((address_space(1))) void*)g,
        (__attribute__((address_space(3))) void*)lds, 16, 0, 0);
}

// ---------------------------------------------------------------------------
// 128x128xK mainloop, BK=32, 256 threads (2x2 waves, each 4x4 MFMA tiles).
// AF32/BF32: 1 = operand is fp32 (stage via cvt8 store), 0 = bf16 (async16).
// ---------------------------------------------------------------------------
template <int AF32, int BF32>
__device__ inline void mainloop(unsigned short* As, unsigned short* Bs,
                                const void* Ap, size_t lda,
                                const void* Bp, size_t ldb,
                                int kIters, floatx4 (&acc)[4][4]) {
    const int t = threadIdx.x, lane = t & 63, wave = t >> 6;
    const int rA = t >> 2, cA = (t & 3) * 8;
    const int mrow = (wave >> 1) * 64, ncol = (wave & 1) * 64;
    const int fr = lane & 15, fk = (lane >> 4) * 8;

    const unsigned short* gA16 = nullptr; const float* gA32 = nullptr;
    const unsigned short* gB16 = nullptr; const float* gB32 = nullptr;
    if (AF32) gA32 = (const float*)Ap + (size_t)rA * lda + cA;
    else      gA16 = (const unsigned short*)Ap + (size_t)rA * lda + cA;
    if (BF32) gB32 = (const float*)Bp + (size_t)rA * ldb + cA;
    else      gB16 = (const unsigned short*)Bp + (size_t)rA * ldb + cA;

    unsigned short* ldsA = As + wave * 512;   // halfwords; second 64 rows at +2048
    unsigned short* ldsB = Bs + wave * 512;

    for (int kt = 0; kt < kIters; ++kt) {
        if (AF32) {
            *(uint4*)&As[t * 8]        = cvt8(gA32);
            *(uint4*)&As[2048 + t * 8] = cvt8(gA32 + 64 * lda);
            gA32 += 32;
        } else {
            async16(ldsA,        gA16);
            async16(ldsA + 2048, gA16 + 64 * lda);
            gA16 += 32;
        }
        if (BF32) {
            *(uint4*)&Bs[t * 8]        = cvt8(gB32);
            *(uint4*)&Bs[2048 + t * 8] = cvt8(gB32 + 64 * ldb);
            gB32 += 32;
        } else {
            async16(ldsB,        gB16);
            async16(ldsB + 2048, gB16 + 64 * ldb);
            gB16 += 32;
        }
        __syncthreads();
        bf16x8 af[4], bfr[4];
#pragma unroll
        for (int i = 0; i < 4; ++i)
            af[i] = *(const bf16x8*)&As[(mrow + i * 16 + fr) * 32 + fk];
#pragma unroll
        for (int j = 0; j < 4; ++j)
            bfr[j] = *(const bf16x8*)&Bs[(ncol + j * 16 + fr) * 32 + fk];
#pragma unroll
        for (int i = 0; i < 4; ++i)
#pragma unroll
            for (int j = 0; j < 4; ++j)
                acc[i][j] = __builtin_amdgcn_mfma_f32_16x16x32_bf16(af[i], bfr[j],
                                                                    acc[i][j], 0, 0, 0);
        __syncthreads();
    }
}

#define EPILOGUE_COORDS                                     \
    const int lane = threadIdx.x & 63, wave = threadIdx.x >> 6; \
    const int mrow = (wave >> 1) * 64, ncol = (wave & 1) * 64;  \
    const int col = lane & 15, q = lane >> 4;

#define ACC_INIT                                            \
    floatx4 acc[4][4];                                      \
    _Pragma("unroll") for (int i = 0; i < 4; ++i)           \
        _Pragma("unroll") for (int j = 0; j < 4; ++j)       \
            acc[i][j] = (floatx4){0.f, 0.f, 0.f, 0.f};

// ---------------------------------------------------------------------------
// k_prep: blocks [0,2048): dst fp32->bf16 flat convert
//         blocks [2048,2176): WT[e][d] = W[d][e]*scl transpose (fused k_wt)
// ---------------------------------------------------------------------------
__global__ __launch_bounds__(256) void k_prep(const float* __restrict__ dst,
                                              unsigned short* __restrict__ dstb,
                                              const float* __restrict__ Wr,
                                              const float* __restrict__ Wv,
                                              unsigned short* __restrict__ WrT,
                                              unsigned short* __restrict__ WvT) {
    __shared__ float Ts[64 * 68];
    const int t = threadIdx.x;
    if (blockIdx.x < 2048) {
        const size_t idx = ((size_t)blockIdx.x * 256 + t) * 8;
        *(uint4*)&dstb[idx] = cvt8(dst + idx);
        return;
    }
    const int n2 = blockIdx.x - 2048;
    const float* W = (n2 >> 6) ? Wv : Wr;
    unsigned short* WT = (n2 >> 6) ? WvT : WrT;
    const float scl = (n2 >> 6) ? 1.f : SCALE;
    const int d0 = (n2 & 7) * 64, e0 = ((n2 >> 3) & 7) * 64;
    {
        const int r = t >> 2, c0 = (t & 3) * 16;
        const float* g = W + (size_t)(d0 + r) * DIM_ + e0 + c0;
#pragma unroll
        for (int i = 0; i < 4; ++i)
            *(float4*)&Ts[r * 68 + c0 + i * 4] = *(const float4*)(g + i * 4);
    }
    __syncthreads();
    {
        const int rr = t >> 2, c0 = (t & 3) * 16;
        unsigned short tmp[16];
#pragma unroll
        for (int j = 0; j < 16; ++j) tmp[j] = f2bf(Ts[(c0 + j) * 68 + rr] * scl);
        unsigned short* o = WT + (size_t)(e0 + rr) * DIM_ + d0 + c0;
        *(uint4*)o = *(const uint4*)tmp;
        *(uint4*)(o + 8) = *(const uint4*)(tmp + 8);
    }
}

// ---------------------------------------------------------------------------
// k_q: Q[s][e] = src[s][:] . WrT[e][:]   (SCALE pre-folded into WrT)
// ---------------------------------------------------------------------------
__global__ __launch_bounds__(256) void k_q(const float* __restrict__ src,
                                           const unsigned short* __restrict__ WrT,
                                           unsigned short* __restrict__ Qb) {
    __shared__ unsigned short As[128 * 32];
    __shared__ unsigned short Bs[128 * 32];
    const int n0 = blockIdx.x * 128, m0 = blockIdx.y * 128;
    ACC_INIT
    mainloop<1, 0>(As, Bs, src + (size_t)m0 * DIM_, DIM_,
                   WrT + (size_t)n0 * DIM_, DIM_, DIM_ / 32, acc);
    EPILOGUE_COORDS
#pragma unroll
    for (int i = 0; i < 4; ++i)
#pragma unroll
        for (int j = 0; j < 4; ++j)
#pragma unroll
            for (int r = 0; r < 4; ++r)
                Qb[(size_t)(m0 + mrow + i * 16 + q * 4 + r) * DIM_ +
                   n0 + ncol + j * 16 + col] = f2bf(acc[i][j][r]);
}

// ---------------------------------------------------------------------------
// k_logitsT: LT[dd][s] = exp(dstb[dd][:] . Q[s][:]) -> bf16  (per batch)
// 1D grid, XCD swizzle: xcd = b (n&7); within XCD consecutive blocks share
// the Q s-tile (B operand stays L2-hot), dstb A-tiles (1MB/b) stay resident.
// Epilogue writes per-(b, dd-tile) column sums Lpart (fp32).
// ---------------------------------------------------------------------------
__global__ __launch_bounds__(256) void k_logitsT(const unsigned short* __restrict__ dstb,
                                                 const unsigned short* __restrict__ Qb,
                                                 unsigned short* __restrict__ LTb,
                                                 float* __restrict__ Lpart) {
    __shared__ unsigned short As[128 * 32];
    __shared__ unsigned short Bs[128 * 32];
    __shared__ float csum[8][128];
    const int n = blockIdx.x;
    const int b = n & 7;          // -> XCD
    const int rem = n >> 3;       // [0,256)
    const int xs = rem >> 3;      // s-tile [0,32), changes slowly (B hot)
    const int yd = rem & 7;       // dd-tile [0,8)
    const int n0 = xs * 128, m0 = yd * 128;
    ACC_INIT
    mainloop<0, 0>(As, Bs,
                   dstb + (size_t)b * DD_ * DIM_ + (size_t)m0 * DIM_, DIM_,
                   Qb + (size_t)b * S_ * DIM_ + (size_t)n0 * DIM_, DIM_,
                   DIM_ / 32, acc);
    EPILOGUE_COORDS
    unsigned short* LT = LTb + (size_t)b * DD_ * S_;
    float psum[4] = {0.f, 0.f, 0.f, 0.f};
#pragma unroll
    for (int i = 0; i < 4; ++i)
#pragma unroll
        for (int j = 0; j < 4; ++j)
#pragma unroll
            for (int r = 0; r < 4; ++r) {
                float e = __expf(acc[i][j][r]);
                LT[(size_t)(m0 + mrow + i * 16 + q * 4 + r) * S_ +
                   n0 + ncol + j * 16 + col] = f2bf(e);
                psum[j] += e;
            }
    const int slice = (wave >> 1) * 4 + q;
#pragma unroll
    for (int j = 0; j < 4; ++j) csum[slice][ncol + j * 16 + col] = psum[j];
    __syncthreads();
    const int t = threadIdx.x;
    if (t < 128) {
        float v = 0.f;
#pragma unroll
        for (int k = 0; k < 8; ++k) v += csum[k][t];
        Lpart[((size_t)b * 8 + yd) * S_ + n0 + t] = v;
    }
}

// ---------------------------------------------------------------------------
// k_finalize: scale[b][s] = softplus(state[b][s]) / sum_tiles Lpart
// ---------------------------------------------------------------------------
__global__ __launch_bounds__(256) void k_finalize(const float* __restrict__ state,
                                                  const float* __restrict__ Lpart,
                                                  float* __restrict__ scale) {
    const int i = blockIdx.x * 256 + threadIdx.x;    // flat b*S+s
    const int b = i >> 12, s = i & (S_ - 1);
    float d = 0.f;
#pragma unroll
    for (int k = 0; k < 8; ++k) d += Lpart[((size_t)b * 8 + k) * S_ + s];
    const float st = state[i];
    const float sp = (st > 15.f) ? st : log1pf(__expf(st));
    scale[i] = sp / d;
}

// ---------------------------------------------------------------------------
// k_pt: PT[e][s] = (WvT[e][:] . src[s][:]) * scale[b][s]   (per batch)
// ---------------------------------------------------------------------------
__global__ __launch_bounds__(256) void k_pt(const unsigned short* __restrict__ WvT,
                                            const float* __restrict__ src,
                                            const float* __restrict__ scale,
                                            unsigned short* __restrict__ PTb) {
    __shared__ unsigned short As[128 * 32];
    __shared__ unsigned short Bs[128 * 32];
    const int n0 = blockIdx.x * 128, m0 = blockIdx.y * 128, b = blockIdx.z;
    ACC_INIT
    mainloop<0, 1>(As, Bs, WvT + (size_t)m0 * DIM_, DIM_,
                   src + (size_t)b * S_ * DIM_ + (size_t)n0 * DIM_, DIM_,
                   DIM_ / 32, acc);
    EPILOGUE_COORDS
    unsigned short* PT = PTb + (size_t)b * DIM_ * S_;
    const float* sc = scale + (size_t)b * S_;
#pragma unroll
    for (int j = 0; j < 4; ++j) {
        const float scj = sc[n0 + ncol + j * 16 + col];
#pragma unroll
        for (int i = 0; i < 4; ++i)
#pragma unroll
            for (int r = 0; r < 4; ++r)
                PT[(size_t)(m0 + mrow + i * 16 + q * 4 + r) * S_ +
                   n0 + ncol + j * 16 + col] = f2bf(acc[i][j][r] * scj);
    }
}

// ---------------------------------------------------------------------------
// k_dval: partial[ks][b][dd][e] = sum_{s slice} LT[dd][s]*PT[e][s], fp16 out
// split-K=4; 1D grid, XCD swizzle: each z=(b,ks) pinned to one XCD
// (working set A 2MB + B 1MB = 3MB < 4MB XCD L2).
// ---------------------------------------------------------------------------
__global__ __launch_bounds__(256) void k_dval(const unsigned short* __restrict__ LTb,
                                              const unsigned short* __restrict__ PTb,
                                              __half* __restrict__ Pp) {
    __shared__ unsigned short As[128 * 32];
    __shared__ unsigned short Bs[128 * 32];
    const int n = blockIdx.x;
    const int z = (n & 7) + 8 * (n >> 8);   // [0,32): (b,ks) -> XCD = n&7
    const int rem = (n >> 3) & 31;
    const int xe = rem >> 3;                // e-tile [0,4), changes slowly
    const int yd = rem & 7;                 // dd-tile [0,8)
    const int b = z >> 2, ks = z & 3;
    const int n0 = xe * 128, m0 = yd * 128;
    ACC_INIT
    mainloop<0, 0>(As, Bs,
                   LTb + (size_t)b * DD_ * S_ + (size_t)m0 * S_ + ks * 1024, S_,
                   PTb + (size_t)b * DIM_ * S_ + (size_t)n0 * S_ + ks * 1024, S_,
                   1024 / 32, acc);
    EPILOGUE_COORDS
    __half* O = Pp + (size_t)ks * B_ * DD_ * DIM_ + (size_t)b * DD_ * DIM_;
#pragma unroll
    for (int i = 0; i < 4; ++i)
#pragma unroll
        for (int j = 0; j < 4; ++j)
#pragma unroll
            for (int r = 0; r < 4; ++r)
                O[(size_t)(m0 + mrow + i * 16 + q * 4 + r) * DIM_ +
                  n0 + ncol + j * 16 + col] = __float2half(acc[i][j][r]);
}

// ---------------------------------------------------------------------------
// k_reduce: d_val = sum of 4 fp16 partial slices
// ---------------------------------------------------------------------------
__global__ __launch_bounds__(256) void k_reduce(const __half* __restrict__ Pp,
                                                float* __restrict__ d_val) {
    const size_t idx = ((size_t)blockIdx.x * 256 + threadIdx.x) * 8;
    const size_t n = (size_t)B_ * DD_ * DIM_;
    float o[8] = {0.f, 0.f, 0.f, 0.f, 0.f, 0.f, 0.f, 0.f};
#pragma unroll
    for (int ks = 0; ks < 4; ++ks) {
        uint4 v = *(const uint4*)(Pp + (size_t)ks * n + idx);
        const __half* h = (const __half*)&v;
#pragma unroll
        for (int j = 0; j < 8; ++j) o[j] += __half2float(h[j]);
    }
    *(float4*)(d_val + idx)     = (float4){o[0], o[1], o[2], o[3]};
    *(float4*)(d_val + idx + 4) = (float4){o[4], o[5], o[6], o[7]};
}

// ---------------------------------------------------------------------------
// k_dstate: delta_state[b][dd] = sum_s LT[dd][s] * scale[b][s] * state[b][s]
// ---------------------------------------------------------------------------
__global__ __launch_bounds__(256) void k_dstate(const unsigned short* __restrict__ LT,
                                                const float* __restrict__ state,
                                                const float* __restrict__ scale,
                                                float* __restrict__ out) {
    const int b = blockIdx.y;
    const int dd = blockIdx.x * 4 + (threadIdx.x >> 6);
    const int lane = threadIdx.x & 63;
    const unsigned short* row = LT + (size_t)b * DD_ * S_ + (size_t)dd * S_;
    const float* st = state + (size_t)b * S_;
    const float* sc = scale + (size_t)b * S_;

    float acc = 0.f;
#pragma unroll
    for (int it = 0; it < S_ / 512; ++it) {
        const int s = it * 512 + lane * 8;
        uint4 v = *(const uint4*)(row + s);
        const unsigned short* e = (const unsigned short*)&v;
        float4 f0 = *(const float4*)(st + s);
        float4 f1 = *(const float4*)(st + s + 4);
        float4 c0 = *(const float4*)(sc + s);
        float4 c1 = *(const float4*)(sc + s + 4);
        acc += bf2f(e[0]) * f0.x * c0.x + bf2f(e[1]) * f0.y * c0.y +
               bf2f(e[2]) * f0.z * c0.z + bf2f(e[3]) * f0.w * c0.w +
               bf2f(e[4]) * f1.x * c1.x + bf2f(e[5]) * f1.y * c1.y +
               bf2f(e[6]) * f1.z * c1.z + bf2f(e[7]) * f1.w * c1.w;
    }
#pragma unroll
    for (int off = 32; off; off >>= 1) acc += __shfl_down(acc, off);
    if (lane == 0) out[(size_t)b * DD_ + dd] = acc;
}

// ---------------------------------------------------------------------------
extern "C" void kernel_launch(void* const* d_in, const int* in_sizes, int n_in,
                              void* d_out, int out_size, void* d_ws, size_t ws_size,
                              hipStream_t stream) {
    const float* src   = (const float*)d_in[0];   // [B,S,DIM]
    const float* state = (const float*)d_in[1];   // [B,S]
    const float* dst   = (const float*)d_in[2];   // [B,D,DIM]
    const float* Wr    = (const float*)d_in[3];   // [DIM,DIM]
    const float* Wv    = (const float*)d_in[4];   // [DIM,DIM]

    // ws layout (128 MiB):
    //  R0 [0,32MB)   Qb [B,S,DIM] bf16 — aliased as PT [B,DIM,S] after k_logitsT
    //  R1 [32,96MB)  LT [B,DD,S]  bf16 exp(logit) — written once, read twice
    //  R2 [96,128MB) early: WrT(.5) WvT(.5) dstb(8) Lpart(1) scale(.125)
    //                late:  Pp fp16 4x8MB (k_dval) — all early readers done by then
    unsigned short* Qb  = (unsigned short*)d_ws;
    unsigned short* PTb = Qb;  // alias — k_pt runs after k_logitsT frees Qb
    unsigned short* LT  = Qb + (size_t)B_ * S_ * DIM_;
    unsigned short* R2  = LT + (size_t)B_ * DD_ * S_;
    unsigned short* WrT = R2;
    unsigned short* WvT = WrT + (size_t)DIM_ * DIM_;
    unsigned short* dstb = WvT + (size_t)DIM_ * DIM_;
    float* Lpart = (float*)(dstb + (size_t)B_ * DD_ * DIM_);  // [B][8][S]
    float* scale = Lpart + (size_t)B_ * 8 * S_;               // [B][S]
    __half* Pp = (__half*)R2;

    float* d_state = (float*)d_out;               // [B, DD]
    float* d_val   = (float*)d_out + B_ * DD_;    // [B, DD, DIM]

    k_prep<<<dim3(2048 + 128), 256, 0, stream>>>(dst, dstb, Wr, Wv, WrT, WvT);
    k_q<<<dim3(DIM_ / 128, (B_ * S_) / 128), 256, 0, stream>>>(src, WrT, Qb);
    k_logitsT<<<dim3(2048), 256, 0, stream>>>(dstb, Qb, LT, Lpart);
    k_finalize<<<dim3((B_ * S_) / 256), 256, 0, stream>>>(state, Lpart, scale);
    k_pt<<<dim3(S_ / 128, DIM_ / 128, B_), 256, 0, stream>>>(WvT, src, scale, PTb);
    k_dstate<<<dim3(DD_ / 4, B_), 256, 0, stream>>>(LT, state, scale, d_state);
    k_dval<<<dim3(1024), 256, 0, stream>>>(LT, PTb, Pp);
    k_reduce<<<dim3((B_ * DD_ * DIM_) / 2048), 256, 0, stream>>>(Pp, d_val);
}

// Round 7
// 297.990 us; speedup vs baseline: 2.6885x; 1.0815x over previous
//
#include <hip/hip_runtime.h>
#include <hip/hip_fp16.h>

#define B_   8
#define S_   4096
#define DD_  1024   // dst nodes
#define DIM_ 512
#define SCALE 0.044194173824159216f  // 1/sqrt(512)

typedef __bf16 bf16x8 __attribute__((ext_vector_type(8)));
typedef float  floatx4 __attribute__((ext_vector_type(4)));

__device__ inline unsigned short f2bf(float f) {
    union { float f; unsigned int u; } v; v.f = f;
    unsigned int r = v.u + 0x7fffu + ((v.u >> 16) & 1u);  // RNE
    return (unsigned short)(r >> 16);
}
__device__ inline float bf2f(unsigned short h) {
    union { unsigned int u; float f; } v; v.u = ((unsigned int)h) << 16;
    return v.f;
}
__device__ inline uint4 cvt8(const float* __restrict__ g) {
    float4 f0 = *(const float4*)g;
    float4 f1 = *(const float4*)(g + 4);
    unsigned short tmp[8] = {f2bf(f0.x), f2bf(f0.y), f2bf(f0.z), f2bf(f0.w),
                             f2bf(f1.x), f2bf(f1.y), f2bf(f1.z), f2bf(f1.w)};
    return *(const uint4*)tmp;
}
// async global->LDS, 16B per lane; lds base must be wave-uniform
__device__ inline void async16(unsigned short* lds, const unsigned short* g) {
    __builtin_amdgcn_global_load_lds(
        (const __attribute__((address_space(1))) void*)g,
        (__attribute__((address_space(3))) void*)lds, 16, 0, 0);
}

// ---------------------------------------------------------------------------
// 128x128xK mainloop, BK=32, 256 threads (2x2 waves, each 4x4 MFMA tiles).
// AF32/BF32: 1 = operand is fp32 (stage via cvt8 store), 0 = bf16 (async16).
// ---------------------------------------------------------------------------
template <int AF32, int BF32>
__device__ inline void mainloop(unsigned short* As, unsigned short* Bs,
                                const void* Ap, size_t lda,
                                const void* Bp, size_t ldb,
                                int kIters, floatx4 (&acc)[4][4]) {
    const int t = threadIdx.x, lane = t & 63, wave = t >> 6;
    const int rA = t >> 2, cA = (t & 3) * 8;
    const int mrow = (wave >> 1) * 64, ncol = (wave & 1) * 64;
    const int fr = lane & 15, fk = (lane >> 4) * 8;

    const unsigned short* gA16 = nullptr; const float* gA32 = nullptr;
    const unsigned short* gB16 = nullptr; const float* gB32 = nullptr;
    if (AF32) gA32 = (const float*)Ap + (size_t)rA * lda + cA;
    else      gA16 = (const unsigned short*)Ap + (size_t)rA * lda + cA;
    if (BF32) gB32 = (const float*)Bp + (size_t)rA * ldb + cA;
    else      gB16 = (const unsigned short*)Bp + (size_t)rA * ldb + cA;

    unsigned short* ldsA = As + wave * 512;   // halfwords; second 64 rows at +2048
    unsigned short* ldsB = Bs + wave * 512;

    for (int kt = 0; kt < kIters; ++kt) {
        if (AF32) {
            *(uint4*)&As[t * 8]        = cvt8(gA32);
            *(uint4*)&As[2048 + t * 8] = cvt8(gA32 + 64 * lda);
            gA32 += 32;
        } else {
            async16(ldsA,        gA16);
            async16(ldsA + 2048, gA16 + 64 * lda);
            gA16 += 32;
        }
        if (BF32) {
            *(uint4*)&Bs[t * 8]        = cvt8(gB32);
            *(uint4*)&Bs[2048 + t * 8] = cvt8(gB32 + 64 * ldb);
            gB32 += 32;
        } else {
            async16(ldsB,        gB16);
            async16(ldsB + 2048, gB16 + 64 * ldb);
            gB16 += 32;
        }
        __syncthreads();
        bf16x8 af[4], bfr[4];
#pragma unroll
        for (int i = 0; i < 4; ++i)
            af[i] = *(const bf16x8*)&As[(mrow + i * 16 + fr) * 32 + fk];
#pragma unroll
        for (int j = 0; j < 4; ++j)
            bfr[j] = *(const bf16x8*)&Bs[(ncol + j * 16 + fr) * 32 + fk];
#pragma unroll
        for (int i = 0; i < 4; ++i)
#pragma unroll
            for (int j = 0; j < 4; ++j)
                acc[i][j] = __builtin_amdgcn_mfma_f32_16x16x32_bf16(af[i], bfr[j],
                                                                    acc[i][j], 0, 0, 0);
        __syncthreads();
    }
}

#define EPILOGUE_COORDS                                     \
    const int lane = threadIdx.x & 63, wave = threadIdx.x >> 6; \
    const int mrow = (wave >> 1) * 64, ncol = (wave & 1) * 64;  \
    const int col = lane & 15, q = lane >> 4;

#define ACC_INIT                                            \
    floatx4 acc[4][4];                                      \
    _Pragma("unroll") for (int i = 0; i < 4; ++i)           \
        _Pragma("unroll") for (int j = 0; j < 4; ++j)       \
            acc[i][j] = (floatx4){0.f, 0.f, 0.f, 0.f};

// ---------------------------------------------------------------------------
// k_prep: blocks [0,8192): srcb = bf16(src); [8192,10240): dstb = bf16(dst)
// ---------------------------------------------------------------------------
__global__ __launch_bounds__(256) void k_prep(const float* __restrict__ src,
                                              unsigned short* __restrict__ srcb,
                                              const float* __restrict__ dst,
                                              unsigned short* __restrict__ dstb) {
    const int t = threadIdx.x;
    if (blockIdx.x < 8192) {
        const size_t idx = ((size_t)blockIdx.x * 256 + t) * 8;
        *(uint4*)&srcb[idx] = cvt8(src + idx);
    } else {
        const size_t idx = ((size_t)(blockIdx.x - 8192) * 256 + t) * 8;
        *(uint4*)&dstb[idx] = cvt8(dst + idx);
    }
}

// ---------------------------------------------------------------------------
// k_dstWr: DW[b*dd][d] = SCALE * sum_e dstb[b*dd][e] * Wr[d][e]
// (logits = src . DW^T — W_route factored onto the small dst side)
// ---------------------------------------------------------------------------
__global__ __launch_bounds__(256) void k_dstWr(const unsigned short* __restrict__ dstb,
                                               const float* __restrict__ Wr,
                                               unsigned short* __restrict__ DW) {
    __shared__ unsigned short As[128 * 32];
    __shared__ unsigned short Bs[128 * 32];
    const int n0 = blockIdx.x * 128, m0 = blockIdx.y * 128;
    ACC_INIT
    mainloop<0, 1>(As, Bs, dstb + (size_t)m0 * DIM_, DIM_,
                   Wr + (size_t)n0 * DIM_, DIM_, DIM_ / 32, acc);
    EPILOGUE_COORDS
#pragma unroll
    for (int i = 0; i < 4; ++i)
#pragma unroll
        for (int j = 0; j < 4; ++j)
#pragma unroll
            for (int r = 0; r < 4; ++r)
                DW[(size_t)(m0 + mrow + i * 16 + q * 4 + r) * DIM_ +
                   n0 + ncol + j * 16 + col] = f2bf(acc[i][j][r] * SCALE);
}

// ---------------------------------------------------------------------------
// k_logitsT: LT[dd][s] = exp(DW[dd][:] . srcb[s][:]) -> bf16  (per batch)
// pure async16 both sides. XCD swizzle: xcd = b; s-tile slow (B L2-hot).
// Epilogue writes per-(b, dd-tile) column sums Lpart (fp32).
// ---------------------------------------------------------------------------
__global__ __launch_bounds__(256) void k_logitsT(const unsigned short* __restrict__ DW,
                                                 const unsigned short* __restrict__ srcb,
                                                 unsigned short* __restrict__ LTb,
                                                 float* __restrict__ Lpart) {
    __shared__ unsigned short As[128 * 32];
    __shared__ unsigned short Bs[128 * 32];
    __shared__ float csum[8][128];
    const int n = blockIdx.x;
    const int b = n & 7;          // -> XCD
    const int rem = n >> 3;       // [0,256)
    const int xs = rem >> 3;      // s-tile [0,32), changes slowly (B hot)
    const int yd = rem & 7;       // dd-tile [0,8)
    const int n0 = xs * 128, m0 = yd * 128;
    ACC_INIT
    mainloop<0, 0>(As, Bs,
                   DW + (size_t)b * DD_ * DIM_ + (size_t)m0 * DIM_, DIM_,
                   srcb + (size_t)b * S_ * DIM_ + (size_t)n0 * DIM_, DIM_,
                   DIM_ / 32, acc);
    EPILOGUE_COORDS
    unsigned short* LT = LTb + (size_t)b * DD_ * S_;
    float psum[4] = {0.f, 0.f, 0.f, 0.f};
#pragma unroll
    for (int i = 0; i < 4; ++i)
#pragma unroll
        for (int j = 0; j < 4; ++j)
#pragma unroll
            for (int r = 0; r < 4; ++r) {
                float e = __expf(acc[i][j][r]);
                LT[(size_t)(m0 + mrow + i * 16 + q * 4 + r) * S_ +
                   n0 + ncol + j * 16 + col] = f2bf(e);
                psum[j] += e;
            }
    const int slice = (wave >> 1) * 4 + q;
#pragma unroll
    for (int j = 0; j < 4; ++j) csum[slice][ncol + j * 16 + col] = psum[j];
    __syncthreads();
    const int t = threadIdx.x;
    if (t < 128) {
        float v = 0.f;
#pragma unroll
        for (int k = 0; k < 8; ++k) v += csum[k][t];
        Lpart[((size_t)b * 8 + yd) * S_ + n0 + t] = v;
    }
}

// ---------------------------------------------------------------------------
// k_finalize: scale[b][s] = softplus(state[b][s]) / sum_tiles Lpart
// (scale parks in d_out's d_val region — fully overwritten by k_dvalW later)
// ---------------------------------------------------------------------------
__global__ __launch_bounds__(256) void k_finalize(const float* __restrict__ state,
                                                  const float* __restrict__ Lpart,
                                                  float* __restrict__ scale) {
    const int i = blockIdx.x * 256 + threadIdx.x;    // flat b*S+s
    const int b = i >> 12, s = i & (S_ - 1);
    float d = 0.f;
#pragma unroll
    for (int k = 0; k < 8; ++k) d += Lpart[((size_t)b * 8 + k) * S_ + s];
    const float st = state[i];
    const float sp = (st > 15.f) ? st : log1pf(__expf(st));
    scale[i] = sp / d;
}

// ---------------------------------------------------------------------------
// k_srcT: srcST[b][d'][s] = bf16( scale[b][s] * srcb[b][s][d'] )
// 64x64 tile transpose through LDS (stride-65 halfword padding).
// ---------------------------------------------------------------------------
__global__ __launch_bounds__(256) void k_srcT(const unsigned short* __restrict__ srcb,
                                              const float* __restrict__ scale,
                                              unsigned short* __restrict__ srcST) {
    __shared__ unsigned short Ts[64 * 65];
    const int s0 = blockIdx.x * 64, d0 = blockIdx.y * 64, b = blockIdx.z;
    const int t = threadIdx.x;
    {
        const int r = t >> 2, c0 = (t & 3) * 16;   // r = s-local, c = d'-local
        const unsigned short* g =
            srcb + (size_t)b * S_ * DIM_ + (size_t)(s0 + r) * DIM_ + d0 + c0;
        uint4 v0 = *(const uint4*)g;
        uint4 v1 = *(const uint4*)(g + 8);
        const unsigned short* e0 = (const unsigned short*)&v0;
        const unsigned short* e1 = (const unsigned short*)&v1;
        const float sc = scale[(size_t)b * S_ + s0 + r];
#pragma unroll
        for (int i = 0; i < 8; ++i) {
            Ts[r * 65 + c0 + i]     = f2bf(bf2f(e0[i]) * sc);
            Ts[r * 65 + c0 + 8 + i] = f2bf(bf2f(e1[i]) * sc);
        }
    }
    __syncthreads();
    {
        const int rr = t >> 2, c0 = (t & 3) * 16;  // rr = d'-local, c = s-local
        unsigned short tmp[16];
#pragma unroll
        for (int j = 0; j < 16; ++j) tmp[j] = Ts[(c0 + j) * 65 + rr];
        unsigned short* o =
            srcST + (size_t)b * DIM_ * S_ + (size_t)(d0 + rr) * S_ + s0 + c0;
        *(uint4*)o = *(const uint4*)tmp;
        *(uint4*)(o + 8) = *(const uint4*)(tmp + 8);
    }
}

// ---------------------------------------------------------------------------
// k_dstate: delta_state[b][dd] = sum_s LT[dd][s] * scale[b][s] * state[b][s]
// ---------------------------------------------------------------------------
__global__ __launch_bounds__(256) void k_dstate(const unsigned short* __restrict__ LT,
                                                const float* __restrict__ state,
                                                const float* __restrict__ scale,
                                                float* __restrict__ out) {
    const int b = blockIdx.y;
    const int dd = blockIdx.x * 4 + (threadIdx.x >> 6);
    const int lane = threadIdx.x & 63;
    const unsigned short* row = LT + (size_t)b * DD_ * S_ + (size_t)dd * S_;
    const float* st = state + (size_t)b * S_;
    const float* sc = scale + (size_t)b * S_;

    float acc = 0.f;
#pragma unroll
    for (int it = 0; it < S_ / 512; ++it) {
        const int s = it * 512 + lane * 8;
        uint4 v = *(const uint4*)(row + s);
        const unsigned short* e = (const unsigned short*)&v;
        float4 f0 = *(const float4*)(st + s);
        float4 f1 = *(const float4*)(st + s + 4);
        float4 c0 = *(const float4*)(sc + s);
        float4 c1 = *(const float4*)(sc + s + 4);
        acc += bf2f(e[0]) * f0.x * c0.x + bf2f(e[1]) * f0.y * c0.y +
               bf2f(e[2]) * f0.z * c0.z + bf2f(e[3]) * f0.w * c0.w +
               bf2f(e[4]) * f1.x * c1.x + bf2f(e[5]) * f1.y * c1.y +
               bf2f(e[6]) * f1.z * c1.z + bf2f(e[7]) * f1.w * c1.w;
    }
#pragma unroll
    for (int off = 32; off; off >>= 1) acc += __shfl_down(acc, off);
    if (lane == 0) out[(size_t)b * DD_ + dd] = acc;
}

// ---------------------------------------------------------------------------
// k_dU: partial[ks][b][dd][d'] = sum_{s slice} LT[dd][s]*srcST[d'][s], fp16
// split-K=4; XCD swizzle: each z=(b,ks) pinned to one XCD (3MB < 4MB L2).
// ---------------------------------------------------------------------------
__global__ __launch_bounds__(256) void k_dU(const unsigned short* __restrict__ LTb,
                                            const unsigned short* __restrict__ srcST,
                                            __half* __restrict__ Pp) {
    __shared__ unsigned short As[128 * 32];
    __shared__ unsigned short Bs[128 * 32];
    const int n = blockIdx.x;
    const int z = (n & 7) + 8 * (n >> 8);   // [0,32): (b,ks) -> XCD = n&7
    const int rem = (n >> 3) & 31;
    const int xe = rem >> 3;                // d'-tile [0,4), changes slowly
    const int yd = rem & 7;                 // dd-tile [0,8)
    const int b = z >> 2, ks = z & 3;
    const int n0 = xe * 128, m0 = yd * 128;
    ACC_INIT
    mainloop<0, 0>(As, Bs,
                   LTb + (size_t)b * DD_ * S_ + (size_t)m0 * S_ + ks * 1024, S_,
                   srcST + (size_t)b * DIM_ * S_ + (size_t)n0 * S_ + ks * 1024, S_,
                   1024 / 32, acc);
    EPILOGUE_COORDS
    __half* O = Pp + (size_t)ks * B_ * DD_ * DIM_ + (size_t)b * DD_ * DIM_;
#pragma unroll
    for (int i = 0; i < 4; ++i)
#pragma unroll
        for (int j = 0; j < 4; ++j)
#pragma unroll
            for (int r = 0; r < 4; ++r)
                O[(size_t)(m0 + mrow + i * 16 + q * 4 + r) * DIM_ +
                  n0 + ncol + j * 16 + col] = __float2half(acc[i][j][r]);
}

// ---------------------------------------------------------------------------
// k_reduceU: blocks [0,2048): U bf16 = sum of 4 fp16 partial slices
//            blocks [2048,2112): WvT[e][d] = bf16(Wv[d][e]) transpose
// ---------------------------------------------------------------------------
__global__ __launch_bounds__(256) void k_reduceU(const __half* __restrict__ Pp,
                                                 unsigned short* __restrict__ U,
                                                 const float* __restrict__ Wv,
                                                 unsigned short* __restrict__ WvT) {
    __shared__ float Ts[64 * 68];
    const int t = threadIdx.x;
    if (blockIdx.x < 2048) {
        const size_t idx = ((size_t)blockIdx.x * 256 + t) * 8;
        const size_t n = (size_t)B_ * DD_ * DIM_;
        float o[8] = {0.f, 0.f, 0.f, 0.f, 0.f, 0.f, 0.f, 0.f};
#pragma unroll
        for (int ks = 0; ks < 4; ++ks) {
            uint4 v = *(const uint4*)(Pp + (size_t)ks * n + idx);
            const __half* h = (const __half*)&v;
#pragma unroll
            for (int j = 0; j < 8; ++j) o[j] += __half2float(h[j]);
        }
        unsigned short tmp[8];
#pragma unroll
        for (int j = 0; j < 8; ++j) tmp[j] = f2bf(o[j]);
        *(uint4*)&U[idx] = *(const uint4*)tmp;
        return;
    }
    const int n2 = blockIdx.x - 2048;
    const int d0 = (n2 & 7) * 64, e0 = (n2 >> 3) * 64;
    {
        const int r = t >> 2, c0 = (t & 3) * 16;
        const float* g = Wv + (size_t)(d0 + r) * DIM_ + e0 + c0;
#pragma unroll
        for (int i = 0; i < 4; ++i)
            *(float4*)&Ts[r * 68 + c0 + i * 4] = *(const float4*)(g + i * 4);
    }
    __syncthreads();
    {
        const int rr = t >> 2, c0 = (t & 3) * 16;
        unsigned short tmp[16];
#pragma unroll
        for (int j = 0; j < 16; ++j) tmp[j] = f2bf(Ts[(c0 + j) * 68 + rr]);
        unsigned short* o = WvT + (size_t)(e0 + rr) * DIM_ + d0 + c0;
        *(uint4*)o = *(const uint4*)tmp;
        *(uint4*)(o + 8) = *(const uint4*)(tmp + 8);
    }
}

// ---------------------------------------------------------------------------
// k_dvalW: d_val[b*dd][e] = sum_d' U[b*dd][d'] * WvT[e][d']   (fp32 out)
// ---------------------------------------------------------------------------
__global__ __launch_bounds__(256) void k_dvalW(const unsigned short* __restrict__ U,
                                               const unsigned short* __restrict__ WvT,
                                               float* __restrict__ d_val) {
    __shared__ unsigned short As[128 * 32];
    __shared__ unsigned short Bs[128 * 32];
    const int n0 = blockIdx.x * 128, m0 = blockIdx.y * 128;
    ACC_INIT
    mainloop<0, 0>(As, Bs, U + (size_t)m0 * DIM_, DIM_,
                   WvT + (size_t)n0 * DIM_, DIM_, DIM_ / 32, acc);
    EPILOGUE_COORDS
#pragma unroll
    for (int i = 0; i < 4; ++i)
#pragma unroll
        for (int j = 0; j < 4; ++j)
#pragma unroll
            for (int r = 0; r < 4; ++r)
                d_val[(size_t)(m0 + mrow + i * 16 + q * 4 + r) * DIM_ +
                      n0 + ncol + j * 16 + col] = acc[i][j][r];
}

// ---------------------------------------------------------------------------
extern "C" void kernel_launch(void* const* d_in, const int* in_sizes, int n_in,
                              void* d_out, int out_size, void* d_ws, size_t ws_size,
                              hipStream_t stream) {
    const float* src   = (const float*)d_in[0];   // [B,S,DIM]
    const float* state = (const float*)d_in[1];   // [B,S]
    const float* dst   = (const float*)d_in[2];   // [B,D,DIM]
    const float* Wr    = (const float*)d_in[3];   // [DIM,DIM]
    const float* Wv    = (const float*)d_in[4];   // [DIM,DIM]

    // ws layout (128 MiB):
    //  A [0,32):  srcb bf16 (prep -> srcT); late: Pp fp16 4x8MiB (dU -> reduceU)
    //  B [32,96): LT bf16 (logitsT -> dU); late: U bf16 (8) + WvT (.5)
    //  C [96,128): early: dstb(8) DW(8) Lpart(1); late: srcST (32, srcT -> dU)
    //  scale parks in d_out's d_val region (overwritten by k_dvalW at the end)
    unsigned short* srcb = (unsigned short*)d_ws;
    __half* Pp = (__half*)d_ws;
    unsigned short* LT = srcb + (size_t)B_ * S_ * DIM_;
    unsigned short* U  = LT;                                   // overlays dead LT
    unsigned short* WvT = U + (size_t)B_ * DD_ * DIM_;
    unsigned short* C = LT + (size_t)B_ * DD_ * S_;
    unsigned short* dstb = C;
    unsigned short* DW = dstb + (size_t)B_ * DD_ * DIM_;
    float* Lpart = (float*)(DW + (size_t)B_ * DD_ * DIM_);     // [B][8][S]
    unsigned short* srcST = C;                                 // overlays dead dstb/DW/Lpart

    float* d_state = (float*)d_out;               // [B, DD]
    float* d_val   = (float*)d_out + B_ * DD_;    // [B, DD, DIM]
    float* scale   = d_val;                       // park (dead before k_dvalW writes)

    k_prep<<<dim3(8192 + 2048), 256, 0, stream>>>(src, srcb, dst, dstb);
    k_dstWr<<<dim3(DIM_ / 128, (B_ * DD_) / 128), 256, 0, stream>>>(dstb, Wr, DW);
    k_logitsT<<<dim3(2048), 256, 0, stream>>>(DW, srcb, LT, Lpart);
    k_finalize<<<dim3((B_ * S_) / 256), 256, 0, stream>>>(state, Lpart, scale);
    k_dstate<<<dim3(DD_ / 4, B_), 256, 0, stream>>>(LT, state, scale, d_state);
    k_srcT<<<dim3(S_ / 64, DIM_ / 64, B_), 256, 0, stream>>>(srcb, scale, srcST);
    k_dU<<<dim3(1024), 256, 0, stream>>>(LT, srcST, Pp);
    k_reduceU<<<dim3(2048 + 64), 256, 0, stream>>>(Pp, U, Wv, WvT);
    k_dvalW<<<dim3(DIM_ / 128, (B_ * DD_) / 128), 256, 0, stream>>>(U, WvT, d_val);
}